// Round 1
// baseline (369.453 us; speedup 1.0000x reference)
//
#include <hip/hip_runtime.h>
#include <hip/hip_bf16.h>

typedef __attribute__((ext_vector_type(8))) short short8;
typedef __attribute__((ext_vector_type(4))) float f32x4;

__device__ __forceinline__ short f2bf(float x) {
  union { float f; unsigned u; } a; a.f = x;
  unsigned r = (a.u + 0x7FFFu + ((a.u >> 16) & 1u)) >> 16;
  return (short)r;
}

// ---------------- K0: small precompute (situation path) ----------------
// sh = Ws@sit + bs ; ck = Wck@sh + bck ; cv = Wcv@sh + bcv
// u[d] = sum_j Wcq[j][d]*ck[j] ; scal[0] = bcq.ck ; scal[1] = cv.wsc
__global__ void ca_pre(const float* __restrict__ sit, const float* __restrict__ Ws,
                       const float* __restrict__ bs, const float* __restrict__ Wck,
                       const float* __restrict__ bck, const float* __restrict__ Wcv,
                       const float* __restrict__ bcv, const float* __restrict__ Wcq,
                       const float* __restrict__ bcq, const float* __restrict__ Wsc,
                       float* __restrict__ u_ws, float* __restrict__ scal) {
  __shared__ float part[4][64];
  __shared__ float sh[64], ck[64], cv[64];
  int t = threadIdx.x;
  int j = t & 63, p = t >> 6;
  float a = 0.f;
  for (int d = p * 96; d < p * 96 + 96; ++d) a += Ws[j * 384 + d] * sit[d];
  part[p][j] = a;
  __syncthreads();
  if (t < 64) sh[t] = part[0][t] + part[1][t] + part[2][t] + part[3][t] + bs[t];
  __syncthreads();
  if (t < 64) {
    float kk = bck[t], vv = bcv[t];
    for (int d = 0; d < 64; ++d) { kk += Wck[t * 64 + d] * sh[d]; vv += Wcv[t * 64 + d] * sh[d]; }
    ck[t] = kk; cv[t] = vv;
  }
  __syncthreads();
  if (t < 64) {
    float uu = 0.f;
    for (int jj = 0; jj < 64; ++jj) uu += Wcq[jj * 64 + t] * ck[jj];
    u_ws[t] = uu;
  }
  if (t == 0) {
    float c0 = 0.f, cw = 0.f;
    for (int jj = 0; jj < 64; ++jj) { c0 += bcq[jj] * ck[jj]; cw += cv[jj] * Wsc[jj]; }
    scal[0] = c0; scal[1] = cw;
  }
}

// ---------------- K1: turn_hidden = [te ; bil] @ Wt^T + bt  ([N][64] f32) ----------------
__global__ __launch_bounds__(256) void ca_hidden(const float* __restrict__ te,
                                                 const float* __restrict__ bil,
                                                 const float* __restrict__ Wt,
                                                 const float* __restrict__ bt,
                                                 float* __restrict__ h, int N) {
  __shared__ float Wl[64 * 98];
  __shared__ float Fl[32 * 98];
  const int t = threadIdx.x;
  const int i0 = blockIdx.x * 32;
  const int cq = t & 15, rg = t >> 4;   // cols cq+16j (j=0..3), rows 2rg,2rg+1
  float acc[2][4] = {{0.f, 0.f, 0.f, 0.f}, {0.f, 0.f, 0.f, 0.f}};
  for (int kc = 0; kc < 4; ++kc) {
    const int k0 = kc * 96;
    const int klen = (kc == 3) ? 97 : 96;
    __syncthreads();
    { int r = t >> 2, sq = t & 3;
      for (int kk = sq; kk < klen; kk += 4) Wl[r * 98 + kk] = Wt[r * 385 + k0 + kk]; }
    { int r = t >> 3, sq = t & 7;
      for (int kk = sq; kk < klen; kk += 8)
        Fl[r * 98 + kk] = (k0 + kk < 384) ? te[(size_t)(i0 + r) * 384 + k0 + kk] : bil[i0 + r]; }
    __syncthreads();
    const int kend = klen & ~1;
    for (int kk = 0; kk < kend; kk += 2) {
      float2 wv[4], fv[2];
#pragma unroll
      for (int jj = 0; jj < 4; ++jj) wv[jj] = *(const float2*)&Wl[(cq + 16 * jj) * 98 + kk];
#pragma unroll
      for (int rr = 0; rr < 2; ++rr) fv[rr] = *(const float2*)&Fl[(rg * 2 + rr) * 98 + kk];
#pragma unroll
      for (int rr = 0; rr < 2; ++rr)
#pragma unroll
        for (int jj = 0; jj < 4; ++jj) {
          acc[rr][jj] += wv[jj].x * fv[rr].x;
          acc[rr][jj] += wv[jj].y * fv[rr].y;
        }
    }
    if (klen & 1) {
      const int kk = kend;
#pragma unroll
      for (int rr = 0; rr < 2; ++rr) {
        float fvs = Fl[(rg * 2 + rr) * 98 + kk];
#pragma unroll
        for (int jj = 0; jj < 4; ++jj) acc[rr][jj] += Wl[(cq + 16 * jj) * 98 + kk] * fvs;
      }
    }
  }
#pragma unroll
  for (int rr = 0; rr < 2; ++rr)
#pragma unroll
    for (int jj = 0; jj < 4; ++jj) {
      int c = cq + 16 * jj;
      h[(size_t)(i0 + rg * 2 + rr) * 64 + c] = acc[rr][jj] + bt[c];
    }
}

// ---------------- K2: q (scaled 1/8), k -> [N][64] bf16 ; v -> transposed [64][N] bf16 ----------------
__global__ __launch_bounds__(256) void ca_qkv(const float* __restrict__ h,
                                              const float* __restrict__ Wq, const float* __restrict__ bq,
                                              const float* __restrict__ Wk, const float* __restrict__ bk2,
                                              const float* __restrict__ Wv, const float* __restrict__ bv,
                                              short* __restrict__ qb, short* __restrict__ kb,
                                              short* __restrict__ vt, int N) {
  __shared__ float Hl[32 * 66];
  __shared__ float Wl[64 * 66];
  __shared__ short Vt[64 * 40];
  const int t = threadIdx.x;
  const int i0 = blockIdx.x * 32;
  for (int idx = t; idx < 2048; idx += 256) {
    int r = idx >> 6, c = idx & 63;
    Hl[r * 66 + c] = h[(size_t)(i0 + r) * 64 + c];
  }
  const int cq = t & 15, rg = t >> 4;
  const int c0 = cq * 4;
  const float* Wm[3] = {Wq, Wk, Wv};
  const float* bm[3] = {bq, bk2, bv};
  for (int m = 0; m < 3; ++m) {
    __syncthreads();
    for (int idx = t; idx < 4096; idx += 256) {
      int c = idx >> 6, k = idx & 63;
      Wl[c * 66 + k] = Wm[m][idx];
    }
    __syncthreads();
    float acc[2][4] = {{0.f, 0.f, 0.f, 0.f}, {0.f, 0.f, 0.f, 0.f}};
    for (int kk = 0; kk < 64; kk += 2) {
      float2 wv[4], hv[2];
#pragma unroll
      for (int jj = 0; jj < 4; ++jj) wv[jj] = *(const float2*)&Wl[(c0 + jj) * 66 + kk];
#pragma unroll
      for (int rr = 0; rr < 2; ++rr) hv[rr] = *(const float2*)&Hl[(rg * 2 + rr) * 66 + kk];
#pragma unroll
      for (int rr = 0; rr < 2; ++rr)
#pragma unroll
        for (int jj = 0; jj < 4; ++jj) {
          acc[rr][jj] += wv[jj].x * hv[rr].x;
          acc[rr][jj] += wv[jj].y * hv[rr].y;
        }
    }
#pragma unroll
    for (int rr = 0; rr < 2; ++rr)
#pragma unroll
      for (int jj = 0; jj < 4; ++jj) acc[rr][jj] += bm[m][c0 + jj];
    if (m == 0) {
#pragma unroll
      for (int rr = 0; rr < 2; ++rr) {
        ushort4 pk;
        pk.x = (unsigned short)f2bf(acc[rr][0] * 0.125f);
        pk.y = (unsigned short)f2bf(acc[rr][1] * 0.125f);
        pk.z = (unsigned short)f2bf(acc[rr][2] * 0.125f);
        pk.w = (unsigned short)f2bf(acc[rr][3] * 0.125f);
        *(ushort4*)&qb[(size_t)(i0 + rg * 2 + rr) * 64 + c0] = pk;
      }
    } else if (m == 1) {
#pragma unroll
      for (int rr = 0; rr < 2; ++rr) {
        ushort4 pk;
        pk.x = (unsigned short)f2bf(acc[rr][0]);
        pk.y = (unsigned short)f2bf(acc[rr][1]);
        pk.z = (unsigned short)f2bf(acc[rr][2]);
        pk.w = (unsigned short)f2bf(acc[rr][3]);
        *(ushort4*)&kb[(size_t)(i0 + rg * 2 + rr) * 64 + c0] = pk;
      }
    } else {
#pragma unroll
      for (int rr = 0; rr < 2; ++rr)
#pragma unroll
        for (int jj = 0; jj < 4; ++jj)
          Vt[(c0 + jj) * 40 + (rg * 2 + rr)] = f2bf(acc[rr][jj]);
      __syncthreads();
      int c = t >> 2, sq = t & 3;
      uint4 val = *(uint4*)&Vt[c * 40 + sq * 8];
      *(uint4*)&vt[(size_t)c * N + i0 + sq * 8] = val;
    }
  }
}

// ---------------- K3: flash attention + residual + cross-attn + score + gate ----------------
// 4 waves/block; wave w handles all 32 queries for key-tiles tt%4==w (split-K, LDS merge).
__global__ __launch_bounds__(256) void ca_attn(
    const float* __restrict__ h, const short* __restrict__ qb, const short* __restrict__ kb,
    const short* __restrict__ vt, const float* __restrict__ u_ws, const float* __restrict__ scal,
    const float* __restrict__ bil, const float* __restrict__ Wsc, const float* __restrict__ bsc_p,
    const float* __restrict__ rgate_p, float* __restrict__ out, int N) {
  __shared__ short Pl[4][32][72];
  __shared__ float Om[4][32][68];
  __shared__ float Ml[4][32][2];
  const int t = threadIdx.x;
  const int lane = t & 63, wid = t >> 6;
  const int g = lane >> 4, li = lane & 15;
  const int q0 = blockIdx.x * 32;

  short8 qa[2][2];
#pragma unroll
  for (int qs = 0; qs < 2; ++qs)
#pragma unroll
    for (int ks = 0; ks < 2; ++ks)
      qa[qs][ks] = *(const short8*)&qb[(size_t)(q0 + qs * 16 + li) * 64 + g * 8 + ks * 32];

  float m[2][4], lsum[2][4];
  f32x4 acc[2][4];
#pragma unroll
  for (int qs = 0; qs < 2; ++qs)
#pragma unroll
    for (int r = 0; r < 4; ++r) {
      m[qs][r] = -1e30f; lsum[qs][r] = 0.f;
      acc[qs][r] = (f32x4){0.f, 0.f, 0.f, 0.f};
    }

  const int ntiles = N >> 6;
  for (int tt = wid; tt < ntiles; tt += 4) {
    const int j0 = tt << 6;
    f32x4 s[2][4];
#pragma unroll
    for (int qs = 0; qs < 2; ++qs)
#pragma unroll
      for (int t4 = 0; t4 < 4; ++t4) s[qs][t4] = (f32x4){0.f, 0.f, 0.f, 0.f};
#pragma unroll
    for (int t4 = 0; t4 < 4; ++t4) {
#pragma unroll
      for (int ks = 0; ks < 2; ++ks) {
        short8 kf = *(const short8*)&kb[(size_t)(j0 + t4 * 16 + li) * 64 + g * 8 + ks * 32];
        s[0][t4] = __builtin_amdgcn_mfma_f32_16x16x32_bf16(qa[0][ks], kf, s[0][t4], 0, 0, 0);
        s[1][t4] = __builtin_amdgcn_mfma_f32_16x16x32_bf16(qa[1][ks], kf, s[1][t4], 0, 0, 0);
      }
    }
#pragma unroll
    for (int qs = 0; qs < 2; ++qs) {
      float mx[4], al[4], rs[4], p[4][4];
#pragma unroll
      for (int r = 0; r < 4; ++r)
        mx[r] = fmaxf(fmaxf(s[qs][0][r], s[qs][1][r]), fmaxf(s[qs][2][r], s[qs][3][r]));
#pragma unroll
      for (int mask = 1; mask < 16; mask <<= 1)
#pragma unroll
        for (int r = 0; r < 4; ++r) mx[r] = fmaxf(mx[r], __shfl_xor(mx[r], mask, 64));
#pragma unroll
      for (int r = 0; r < 4; ++r) {
        float mn = fmaxf(m[qs][r], mx[r]);
        al[r] = __expf(m[qs][r] - mn);
        m[qs][r] = mn;
      }
#pragma unroll
      for (int t4 = 0; t4 < 4; ++t4)
#pragma unroll
        for (int r = 0; r < 4; ++r) p[t4][r] = __expf(s[qs][t4][r] - m[qs][r]);
#pragma unroll
      for (int r = 0; r < 4; ++r) rs[r] = (p[0][r] + p[1][r]) + (p[2][r] + p[3][r]);
#pragma unroll
      for (int mask = 1; mask < 16; mask <<= 1)
#pragma unroll
        for (int r = 0; r < 4; ++r) rs[r] += __shfl_xor(rs[r], mask, 64);
#pragma unroll
      for (int r = 0; r < 4; ++r) lsum[qs][r] = lsum[qs][r] * al[r] + rs[r];
#pragma unroll
      for (int t4 = 0; t4 < 4; ++t4)
#pragma unroll
        for (int r = 0; r < 4; ++r) acc[qs][t4][r] *= al[r];
#pragma unroll
      for (int t4 = 0; t4 < 4; ++t4)
#pragma unroll
        for (int r = 0; r < 4; ++r)
          Pl[wid][qs * 16 + g * 4 + r][li + t4 * 16] = f2bf(p[t4][r]);
    }
    asm volatile("s_waitcnt lgkmcnt(0)" ::: "memory");
#pragma unroll
    for (int ks2 = 0; ks2 < 2; ++ks2) {
      short8 pa0 = *(const short8*)&Pl[wid][li][g * 8 + ks2 * 32];
      short8 pa1 = *(const short8*)&Pl[wid][li + 16][g * 8 + ks2 * 32];
#pragma unroll
      for (int dt = 0; dt < 4; ++dt) {
        short8 vf = *(const short8*)&vt[(size_t)(li + dt * 16) * N + j0 + ks2 * 32 + g * 8];
        acc[0][dt] = __builtin_amdgcn_mfma_f32_16x16x32_bf16(pa0, vf, acc[0][dt], 0, 0, 0);
        acc[1][dt] = __builtin_amdgcn_mfma_f32_16x16x32_bf16(pa1, vf, acc[1][dt], 0, 0, 0);
      }
    }
  }
  // write per-wave partials
#pragma unroll
  for (int qs = 0; qs < 2; ++qs)
#pragma unroll
    for (int dt = 0; dt < 4; ++dt)
#pragma unroll
      for (int r = 0; r < 4; ++r)
        Om[wid][qs * 16 + g * 4 + r][li + dt * 16] = acc[qs][dt][r];
  if (li == 0) {
#pragma unroll
    for (int qs = 0; qs < 2; ++qs)
#pragma unroll
      for (int r = 0; r < 4; ++r) {
        Ml[wid][qs * 16 + g * 4 + r][0] = m[qs][r];
        Ml[wid][qs * 16 + g * 4 + r][1] = lsum[qs][r];
      }
  }
  __syncthreads();
  // merge 4 partials + fused epilogue; thread t: q-row t>>3, d-chunk (t&7)*8
  const int ql = t >> 3, e = t & 7, d0 = e * 8;
  float M = -1e30f;
#pragma unroll
  for (int w = 0; w < 4; ++w) M = fmaxf(M, Ml[w][ql][0]);
  float L = 0.f, o[8];
#pragma unroll
  for (int i = 0; i < 8; ++i) o[i] = 0.f;
#pragma unroll
  for (int w = 0; w < 4; ++w) {
    float aw = __expf(Ml[w][ql][0] - M);
    L += Ml[w][ql][1] * aw;
#pragma unroll
    for (int i = 0; i < 8; ++i) o[i] += Om[w][ql][d0 + i] * aw;
  }
  const float invL = 1.f / L;
  float s1 = 0.f, s2 = 0.f;
#pragma unroll
  for (int i = 0; i < 8; ++i) {
    float h2 = h[(size_t)(q0 + ql) * 64 + d0 + i] + o[i] * invL;
    s1 += h2 * u_ws[d0 + i];
    s2 += h2 * Wsc[d0 + i];
  }
#pragma unroll
  for (int mask = 1; mask < 8; mask <<= 1) {
    s1 += __shfl_xor(s1, mask, 64);
    s2 += __shfl_xor(s2, mask, 64);
  }
  if (e == 0) {
    float gate = 1.f / (1.f + __expf(-rgate_p[0]));
    float caw = 1.f / (1.f + __expf(-(s1 + scal[0]) * 0.125f));
    float score = s2 + caw * scal[1] + bsc_p[0];
    out[q0 + ql] = (1.f - gate) * bil[q0 + ql] + gate * score;
  }
}

extern "C" void kernel_launch(void* const* d_in, const int* in_sizes, int n_in,
                              void* d_out, int out_size, void* d_ws, size_t ws_size,
                              hipStream_t stream) {
  const float* sit  = (const float*)d_in[0];
  const float* te   = (const float*)d_in[1];
  const float* bil  = (const float*)d_in[2];
  const float* Wt   = (const float*)d_in[3];
  const float* bt   = (const float*)d_in[4];
  const float* Ws   = (const float*)d_in[5];
  const float* bs   = (const float*)d_in[6];
  const float* Wsaq = (const float*)d_in[7];
  const float* bsaq = (const float*)d_in[8];
  const float* Wsak = (const float*)d_in[9];
  const float* bsak = (const float*)d_in[10];
  const float* Wsav = (const float*)d_in[11];
  const float* bsav = (const float*)d_in[12];
  const float* Wcq  = (const float*)d_in[13];
  const float* bcq  = (const float*)d_in[14];
  const float* Wck  = (const float*)d_in[15];
  const float* bck  = (const float*)d_in[16];
  const float* Wcv  = (const float*)d_in[17];
  const float* bcv  = (const float*)d_in[18];
  const float* Wsc  = (const float*)d_in[19];
  const float* bsc  = (const float*)d_in[20];
  const float* rgate= (const float*)d_in[21];
  const int N = in_sizes[2];

  char* w = (char*)d_ws;
  float* h     = (float*)w;                                   // N*64 f32
  short* qbuf  = (short*)(w + (size_t)N * 64 * 4);            // N*64 bf16
  short* kbuf  = qbuf + (size_t)N * 64;                       // N*64 bf16
  short* vtbuf = kbuf + (size_t)N * 64;                       // 64*N bf16 (transposed)
  float* u_ws  = (float*)(w + (size_t)N * 64 * 4 + (size_t)N * 64 * 2 * 3);
  float* scal  = u_ws + 64;

  ca_pre<<<1, 256, 0, stream>>>(sit, Ws, bs, Wck, bck, Wcv, bcv, Wcq, bcq, Wsc, u_ws, scal);
  ca_hidden<<<N / 32, 256, 0, stream>>>(te, bil, Wt, bt, h, N);
  ca_qkv<<<N / 32, 256, 0, stream>>>(h, Wsaq, bsaq, Wsak, bsak, Wsav, bsav, qbuf, kbuf, vtbuf, N);
  ca_attn<<<N / 32, 256, 0, stream>>>(h, qbuf, kbuf, vtbuf, u_ws, scal, bil, Wsc, bsc, rgate,
                                      (float*)d_out, N);
}

// Round 2
// 194.736 us; speedup vs baseline: 1.8972x; 1.8972x over previous
//
#include <hip/hip_runtime.h>
#include <hip/hip_bf16.h>

typedef __attribute__((ext_vector_type(8))) short short8;
typedef __attribute__((ext_vector_type(4))) float f32x4;

__device__ __forceinline__ short f2bf(float x) {
  union { float f; unsigned u; } a; a.f = x;
  unsigned r = (a.u + 0x7FFFu + ((a.u >> 16) & 1u)) >> 16;
  return (short)r;
}

// ---------------- K0: small precompute (situation path) ----------------
__global__ void ca_pre(const float* __restrict__ sit, const float* __restrict__ Ws,
                       const float* __restrict__ bs, const float* __restrict__ Wck,
                       const float* __restrict__ bck, const float* __restrict__ Wcv,
                       const float* __restrict__ bcv, const float* __restrict__ Wcq,
                       const float* __restrict__ bcq, const float* __restrict__ Wsc,
                       float* __restrict__ u_ws, float* __restrict__ scal) {
  __shared__ float part[4][64];
  __shared__ float sh[64], ck[64], cv[64];
  int t = threadIdx.x;
  int j = t & 63, p = t >> 6;
  float a = 0.f;
  for (int d = p * 96; d < p * 96 + 96; ++d) a += Ws[j * 384 + d] * sit[d];
  part[p][j] = a;
  __syncthreads();
  if (t < 64) sh[t] = part[0][t] + part[1][t] + part[2][t] + part[3][t] + bs[t];
  __syncthreads();
  if (t < 64) {
    float kk = bck[t], vv = bcv[t];
    for (int d = 0; d < 64; ++d) { kk += Wck[t * 64 + d] * sh[d]; vv += Wcv[t * 64 + d] * sh[d]; }
    ck[t] = kk; cv[t] = vv;
  }
  __syncthreads();
  if (t < 64) {
    float uu = 0.f;
    for (int jj = 0; jj < 64; ++jj) uu += Wcq[jj * 64 + t] * ck[jj];
    u_ws[t] = uu;
  }
  if (t == 0) {
    float c0 = 0.f, cw = 0.f;
    for (int jj = 0; jj < 64; ++jj) { c0 += bcq[jj] * ck[jj]; cw += cv[jj] * Wsc[jj]; }
    scal[0] = c0; scal[1] = cw;
  }
}

// ---------------- K0b: weight conversion to bf16 ----------------
__global__ __launch_bounds__(256) void ca_conv(const float* __restrict__ Wt,
    const float* __restrict__ Wsaq, const float* __restrict__ Wsak, const float* __restrict__ Wsav,
    short* __restrict__ Wtb, float* __restrict__ wcol,
    short* __restrict__ Wqb, short* __restrict__ Wkb, short* __restrict__ Wvb) {
  int idx = blockIdx.x * 256 + threadIdx.x;
  if (idx < 24576) {
    int r = idx / 384, c = idx % 384;
    Wtb[idx] = f2bf(Wt[r * 385 + c]);
  } else if (idx < 24640) {
    wcol[idx - 24576] = Wt[(idx - 24576) * 385 + 384];
  } else if (idx < 28736) {
    Wqb[idx - 24640] = f2bf(Wsaq[idx - 24640]);
  } else if (idx < 32832) {
    Wkb[idx - 28736] = f2bf(Wsak[idx - 28736]);
  } else if (idx < 36928) {
    Wvb[idx - 32832] = f2bf(Wsav[idx - 32832]);
  }
}

// ---------------- K1: turn_hidden via MFMA (K=384 GEMM + rank-1 bil term) ----------------
// grid N/32, block 128 (2 waves x 16 rows). Outputs h (fp32) and hb (bf16).
__global__ __launch_bounds__(128) void ca_hidden2(const float* __restrict__ te,
                                                  const float* __restrict__ bil,
                                                  const short* __restrict__ Wtb,
                                                  const float* __restrict__ wcol,
                                                  const float* __restrict__ bt,
                                                  float* __restrict__ h, short* __restrict__ hb,
                                                  int N) {
  const int t = threadIdx.x, lane = t & 63, w = t >> 6;
  const int g = lane >> 4, li = lane & 15;
  const int i0 = blockIdx.x * 32 + w * 16;
  f32x4 acc[4];
#pragma unroll
  for (int n = 0; n < 4; ++n) acc[n] = (f32x4){0.f, 0.f, 0.f, 0.f};
  const float* arow = te + (size_t)(i0 + li) * 384 + g * 8;
  for (int ks = 0; ks < 12; ++ks) {
    float4 a0 = *(const float4*)(arow + ks * 32);
    float4 a1 = *(const float4*)(arow + ks * 32 + 4);
    short8 af;
    af[0] = f2bf(a0.x); af[1] = f2bf(a0.y); af[2] = f2bf(a0.z); af[3] = f2bf(a0.w);
    af[4] = f2bf(a1.x); af[5] = f2bf(a1.y); af[6] = f2bf(a1.z); af[7] = f2bf(a1.w);
#pragma unroll
    for (int n = 0; n < 4; ++n) {
      short8 bf = *(const short8*)&Wtb[(size_t)(n * 16 + li) * 384 + ks * 32 + g * 8];
      acc[n] = __builtin_amdgcn_mfma_f32_16x16x32_bf16(af, bf, acc[n], 0, 0, 0);
    }
  }
#pragma unroll
  for (int n = 0; n < 4; ++n) {
    int col = n * 16 + li;
    float bb = bt[col], wc = wcol[col];
#pragma unroll
    for (int r = 0; r < 4; ++r) {
      int R = i0 + g * 4 + r;
      float val = acc[n][r] + bb + bil[R] * wc;
      h[(size_t)R * 64 + col] = val;
      hb[(size_t)R * 64 + col] = f2bf(val);
    }
  }
}

// ---------------- K2: q/k/v projections via MFMA ----------------
// grid N/32, block 128. q scaled 1/8 -> bf16 [N][64]; k -> bf16 [N][64]; v -> vt [64][N].
__global__ __launch_bounds__(128) void ca_qkv2(const short* __restrict__ hb,
    const short* __restrict__ Wqb, const float* __restrict__ bq,
    const short* __restrict__ Wkb, const float* __restrict__ bk2,
    const short* __restrict__ Wvb, const float* __restrict__ bv,
    short* __restrict__ qb, short* __restrict__ kb, short* __restrict__ vt, int N) {
  __shared__ short Vt[64][40];
  const int t = threadIdx.x, lane = t & 63, w = t >> 6;
  const int g = lane >> 4, li = lane & 15;
  const int ib = blockIdx.x * 32;
  const int i0 = ib + w * 16;
  short8 ha[2];
  ha[0] = *(const short8*)&hb[(size_t)(i0 + li) * 64 + g * 8];
  ha[1] = *(const short8*)&hb[(size_t)(i0 + li) * 64 + g * 8 + 32];
  const short* Wm[3] = {Wqb, Wkb, Wvb};
  const float* bm[3] = {bq, bk2, bv};
  for (int m = 0; m < 3; ++m) {
    f32x4 acc[4];
#pragma unroll
    for (int n = 0; n < 4; ++n) acc[n] = (f32x4){0.f, 0.f, 0.f, 0.f};
#pragma unroll
    for (int n = 0; n < 4; ++n)
#pragma unroll
      for (int ks = 0; ks < 2; ++ks) {
        short8 bf = *(const short8*)&Wm[m][(size_t)(n * 16 + li) * 64 + ks * 32 + g * 8];
        acc[n] = __builtin_amdgcn_mfma_f32_16x16x32_bf16(ha[ks], bf, acc[n], 0, 0, 0);
      }
    if (m == 0) {
#pragma unroll
      for (int n = 0; n < 4; ++n) {
        int col = n * 16 + li;
        float bb = bq[col];
#pragma unroll
        for (int r = 0; r < 4; ++r)
          qb[(size_t)(i0 + g * 4 + r) * 64 + col] = f2bf((acc[n][r] + bb) * 0.125f);
      }
    } else if (m == 1) {
#pragma unroll
      for (int n = 0; n < 4; ++n) {
        int col = n * 16 + li;
        float bb = bk2[col];
#pragma unroll
        for (int r = 0; r < 4; ++r)
          kb[(size_t)(i0 + g * 4 + r) * 64 + col] = f2bf(acc[n][r] + bb);
      }
    } else {
#pragma unroll
      for (int n = 0; n < 4; ++n) {
        int col = n * 16 + li;
        float bb = bv[col];
#pragma unroll
        for (int r = 0; r < 4; ++r)
          Vt[col][w * 16 + g * 4 + r] = f2bf(acc[n][r] + bb);
      }
    }
  }
  __syncthreads();
  const int c = t >> 1, half = t & 1;
  *(uint4*)&vt[(size_t)c * N + ib + half * 16] = *(uint4*)&Vt[c][half * 16];
  *(uint4*)&vt[(size_t)c * N + ib + half * 16 + 8] = *(uint4*)&Vt[c][half * 16 + 8];
}

// ---------------- K3: flash attention + residual + cross-attn + score + gate ----------------
__global__ __launch_bounds__(256) void ca_attn(
    const float* __restrict__ h, const short* __restrict__ qb, const short* __restrict__ kb,
    const short* __restrict__ vt, const float* __restrict__ u_ws, const float* __restrict__ scal,
    const float* __restrict__ bil, const float* __restrict__ Wsc, const float* __restrict__ bsc_p,
    const float* __restrict__ rgate_p, float* __restrict__ out, int N) {
  __shared__ short Pl[4][32][72];
  __shared__ float Om[4][32][68];
  __shared__ float Ml[4][32][2];
  const int t = threadIdx.x;
  const int lane = t & 63, wid = t >> 6;
  const int g = lane >> 4, li = lane & 15;
  const int q0 = blockIdx.x * 32;

  short8 qa[2][2];
#pragma unroll
  for (int qs = 0; qs < 2; ++qs)
#pragma unroll
    for (int ks = 0; ks < 2; ++ks)
      qa[qs][ks] = *(const short8*)&qb[(size_t)(q0 + qs * 16 + li) * 64 + g * 8 + ks * 32];

  float m[2][4], lsum[2][4];
  f32x4 acc[2][4];
#pragma unroll
  for (int qs = 0; qs < 2; ++qs)
#pragma unroll
    for (int r = 0; r < 4; ++r) {
      m[qs][r] = -1e30f; lsum[qs][r] = 0.f;
      acc[qs][r] = (f32x4){0.f, 0.f, 0.f, 0.f};
    }

  const int ntiles = N >> 6;
  for (int tt = wid; tt < ntiles; tt += 4) {
    const int j0 = tt << 6;
    f32x4 s[2][4];
#pragma unroll
    for (int qs = 0; qs < 2; ++qs)
#pragma unroll
      for (int t4 = 0; t4 < 4; ++t4) s[qs][t4] = (f32x4){0.f, 0.f, 0.f, 0.f};
#pragma unroll
    for (int t4 = 0; t4 < 4; ++t4) {
#pragma unroll
      for (int ks = 0; ks < 2; ++ks) {
        short8 kf = *(const short8*)&kb[(size_t)(j0 + t4 * 16 + li) * 64 + g * 8 + ks * 32];
        s[0][t4] = __builtin_amdgcn_mfma_f32_16x16x32_bf16(qa[0][ks], kf, s[0][t4], 0, 0, 0);
        s[1][t4] = __builtin_amdgcn_mfma_f32_16x16x32_bf16(qa[1][ks], kf, s[1][t4], 0, 0, 0);
      }
    }
#pragma unroll
    for (int qs = 0; qs < 2; ++qs) {
      float mx[4], al[4], rs[4], p[4][4];
#pragma unroll
      for (int r = 0; r < 4; ++r)
        mx[r] = fmaxf(fmaxf(s[qs][0][r], s[qs][1][r]), fmaxf(s[qs][2][r], s[qs][3][r]));
#pragma unroll
      for (int mask = 1; mask < 16; mask <<= 1)
#pragma unroll
        for (int r = 0; r < 4; ++r) mx[r] = fmaxf(mx[r], __shfl_xor(mx[r], mask, 64));
#pragma unroll
      for (int r = 0; r < 4; ++r) {
        float mn = fmaxf(m[qs][r], mx[r]);
        al[r] = __expf(m[qs][r] - mn);
        m[qs][r] = mn;
      }
#pragma unroll
      for (int t4 = 0; t4 < 4; ++t4)
#pragma unroll
        for (int r = 0; r < 4; ++r) p[t4][r] = __expf(s[qs][t4][r] - m[qs][r]);
#pragma unroll
      for (int r = 0; r < 4; ++r) rs[r] = (p[0][r] + p[1][r]) + (p[2][r] + p[3][r]);
#pragma unroll
      for (int mask = 1; mask < 16; mask <<= 1)
#pragma unroll
        for (int r = 0; r < 4; ++r) rs[r] += __shfl_xor(rs[r], mask, 64);
#pragma unroll
      for (int r = 0; r < 4; ++r) lsum[qs][r] = lsum[qs][r] * al[r] + rs[r];
#pragma unroll
      for (int t4 = 0; t4 < 4; ++t4)
#pragma unroll
        for (int r = 0; r < 4; ++r) acc[qs][t4][r] *= al[r];
#pragma unroll
      for (int t4 = 0; t4 < 4; ++t4)
#pragma unroll
        for (int r = 0; r < 4; ++r)
          Pl[wid][qs * 16 + g * 4 + r][li + t4 * 16] = f2bf(p[t4][r]);
    }
    asm volatile("s_waitcnt lgkmcnt(0)" ::: "memory");
#pragma unroll
    for (int ks2 = 0; ks2 < 2; ++ks2) {
      short8 pa0 = *(const short8*)&Pl[wid][li][g * 8 + ks2 * 32];
      short8 pa1 = *(const short8*)&Pl[wid][li + 16][g * 8 + ks2 * 32];
#pragma unroll
      for (int dt = 0; dt < 4; ++dt) {
        short8 vf = *(const short8*)&vt[(size_t)(li + dt * 16) * N + j0 + ks2 * 32 + g * 8];
        acc[0][dt] = __builtin_amdgcn_mfma_f32_16x16x32_bf16(pa0, vf, acc[0][dt], 0, 0, 0);
        acc[1][dt] = __builtin_amdgcn_mfma_f32_16x16x32_bf16(pa1, vf, acc[1][dt], 0, 0, 0);
      }
    }
  }
#pragma unroll
  for (int qs = 0; qs < 2; ++qs)
#pragma unroll
    for (int dt = 0; dt < 4; ++dt)
#pragma unroll
      for (int r = 0; r < 4; ++r)
        Om[wid][qs * 16 + g * 4 + r][li + dt * 16] = acc[qs][dt][r];
  if (li == 0) {
#pragma unroll
    for (int qs = 0; qs < 2; ++qs)
#pragma unroll
      for (int r = 0; r < 4; ++r) {
        Ml[wid][qs * 16 + g * 4 + r][0] = m[qs][r];
        Ml[wid][qs * 16 + g * 4 + r][1] = lsum[qs][r];
      }
  }
  __syncthreads();
  const int ql = t >> 3, e = t & 7, d0 = e * 8;
  float M = -1e30f;
#pragma unroll
  for (int w = 0; w < 4; ++w) M = fmaxf(M, Ml[w][ql][0]);
  float L = 0.f, o[8];
#pragma unroll
  for (int i = 0; i < 8; ++i) o[i] = 0.f;
#pragma unroll
  for (int w = 0; w < 4; ++w) {
    float aw = __expf(Ml[w][ql][0] - M);
    L += Ml[w][ql][1] * aw;
#pragma unroll
    for (int i = 0; i < 8; ++i) o[i] += Om[w][ql][d0 + i] * aw;
  }
  const float invL = 1.f / L;
  float s1 = 0.f, s2 = 0.f;
#pragma unroll
  for (int i = 0; i < 8; ++i) {
    float h2 = h[(size_t)(q0 + ql) * 64 + d0 + i] + o[i] * invL;
    s1 += h2 * u_ws[d0 + i];
    s2 += h2 * Wsc[d0 + i];
  }
#pragma unroll
  for (int mask = 1; mask < 8; mask <<= 1) {
    s1 += __shfl_xor(s1, mask, 64);
    s2 += __shfl_xor(s2, mask, 64);
  }
  if (e == 0) {
    float gate = 1.f / (1.f + __expf(-rgate_p[0]));
    float caw = 1.f / (1.f + __expf(-(s1 + scal[0]) * 0.125f));
    float score = s2 + caw * scal[1] + bsc_p[0];
    out[q0 + ql] = (1.f - gate) * bil[q0 + ql] + gate * score;
  }
}

extern "C" void kernel_launch(void* const* d_in, const int* in_sizes, int n_in,
                              void* d_out, int out_size, void* d_ws, size_t ws_size,
                              hipStream_t stream) {
  const float* sit  = (const float*)d_in[0];
  const float* te   = (const float*)d_in[1];
  const float* bil  = (const float*)d_in[2];
  const float* Wt   = (const float*)d_in[3];
  const float* bt   = (const float*)d_in[4];
  const float* Ws   = (const float*)d_in[5];
  const float* bs   = (const float*)d_in[6];
  const float* Wsaq = (const float*)d_in[7];
  const float* bsaq = (const float*)d_in[8];
  const float* Wsak = (const float*)d_in[9];
  const float* bsak = (const float*)d_in[10];
  const float* Wsav = (const float*)d_in[11];
  const float* bsav = (const float*)d_in[12];
  const float* Wcq  = (const float*)d_in[13];
  const float* bcq  = (const float*)d_in[14];
  const float* Wck  = (const float*)d_in[15];
  const float* bck  = (const float*)d_in[16];
  const float* Wcv  = (const float*)d_in[17];
  const float* bcv  = (const float*)d_in[18];
  const float* Wsc  = (const float*)d_in[19];
  const float* bsc  = (const float*)d_in[20];
  const float* rgate= (const float*)d_in[21];
  const int N = in_sizes[2];

  char* w = (char*)d_ws;
  size_t off = 0;
  float* h     = (float*)(w + off); off += (size_t)N * 64 * 4;
  short* hbuf  = (short*)(w + off); off += (size_t)N * 64 * 2;
  short* qbuf  = (short*)(w + off); off += (size_t)N * 64 * 2;
  short* kbuf  = (short*)(w + off); off += (size_t)N * 64 * 2;
  short* vtbuf = (short*)(w + off); off += (size_t)N * 64 * 2;
  float* u_ws  = (float*)(w + off); off += 64 * 4;
  float* scal  = (float*)(w + off); off += 4 * 4;
  short* Wtb   = (short*)(w + off); off += 24576 * 2;
  float* wcol  = (float*)(w + off); off += 64 * 4;
  short* Wqb   = (short*)(w + off); off += 4096 * 2;
  short* Wkb   = (short*)(w + off); off += 4096 * 2;
  short* Wvb   = (short*)(w + off); off += 4096 * 2;

  ca_pre<<<1, 256, 0, stream>>>(sit, Ws, bs, Wck, bck, Wcv, bcv, Wcq, bcq, Wsc, u_ws, scal);
  ca_conv<<<145, 256, 0, stream>>>(Wt, Wsaq, Wsak, Wsav, Wtb, wcol, Wqb, Wkb, Wvb);
  ca_hidden2<<<N / 32, 128, 0, stream>>>(te, bil, Wtb, wcol, bt, h, hbuf, N);
  ca_qkv2<<<N / 32, 128, 0, stream>>>(hbuf, Wqb, bsaq, Wkb, bsak, Wvb, bsav,
                                      qbuf, kbuf, vtbuf, N);
  ca_attn<<<N / 32, 256, 0, stream>>>(h, qbuf, kbuf, vtbuf, u_ws, scal, bil, Wsc, bsc, rgate,
                                      (float*)d_out, N);
}

// Round 3
// 157.491 us; speedup vs baseline: 2.3459x; 1.2365x over previous
//
#include <hip/hip_runtime.h>
#include <hip/hip_bf16.h>

typedef __attribute__((ext_vector_type(8))) short short8;
typedef __attribute__((ext_vector_type(4))) float f32x4;

__device__ __forceinline__ short f2bf(float x) {
  union { float f; unsigned u; } a; a.f = x;
  unsigned r = (a.u + 0x7FFFu + ((a.u >> 16) & 1u)) >> 16;
  return (short)r;
}
__device__ __forceinline__ float bf2f(short x) {
  union { unsigned u; float f; } a; a.u = ((unsigned)(unsigned short)x) << 16;
  return a.f;
}

// ---------------- K0: small precompute (situation path) ----------------
__global__ void ca_pre(const float* __restrict__ sit, const float* __restrict__ Ws,
                       const float* __restrict__ bs, const float* __restrict__ Wck,
                       const float* __restrict__ bck, const float* __restrict__ Wcv,
                       const float* __restrict__ bcv, const float* __restrict__ Wcq,
                       const float* __restrict__ bcq, const float* __restrict__ Wsc,
                       float* __restrict__ u_ws, float* __restrict__ scal) {
  __shared__ float part[4][64];
  __shared__ float sh[64], ck[64], cv[64];
  int t = threadIdx.x;
  int j = t & 63, p = t >> 6;
  float a = 0.f;
  for (int d = p * 96; d < p * 96 + 96; ++d) a += Ws[j * 384 + d] * sit[d];
  part[p][j] = a;
  __syncthreads();
  if (t < 64) sh[t] = part[0][t] + part[1][t] + part[2][t] + part[3][t] + bs[t];
  __syncthreads();
  if (t < 64) {
    float kk = bck[t], vv = bcv[t];
    for (int d = 0; d < 64; ++d) { kk += Wck[t * 64 + d] * sh[d]; vv += Wcv[t * 64 + d] * sh[d]; }
    ck[t] = kk; cv[t] = vv;
  }
  __syncthreads();
  if (t < 64) {
    float uu = 0.f;
    for (int jj = 0; jj < 64; ++jj) uu += Wcq[jj * 64 + t] * ck[jj];
    u_ws[t] = uu;
  }
  if (t == 0) {
    float c0 = 0.f, cw = 0.f;
    for (int jj = 0; jj < 64; ++jj) { c0 += bcq[jj] * ck[jj]; cw += cv[jj] * Wsc[jj]; }
    scal[0] = c0; scal[1] = cw;
  }
}

// ---------------- K0b: weight conversion to bf16 ----------------
__global__ __launch_bounds__(256) void ca_conv(const float* __restrict__ Wt,
    const float* __restrict__ Wsaq, const float* __restrict__ Wsak, const float* __restrict__ Wsav,
    short* __restrict__ Wtb, float* __restrict__ wcol,
    short* __restrict__ Wqb, short* __restrict__ Wkb, short* __restrict__ Wvb) {
  int idx = blockIdx.x * 256 + threadIdx.x;
  if (idx < 24576) {
    int r = idx / 384, c = idx % 384;
    Wtb[idx] = f2bf(Wt[r * 385 + c]);
  } else if (idx < 24640) {
    wcol[idx - 24576] = Wt[(idx - 24576) * 385 + 384];
  } else if (idx < 28736) {
    Wqb[idx - 24640] = f2bf(Wsaq[idx - 24640]);
  } else if (idx < 32832) {
    Wkb[idx - 28736] = f2bf(Wsak[idx - 28736]);
  } else if (idx < 36928) {
    Wvb[idx - 32832] = f2bf(Wsav[idx - 32832]);
  }
}

// ---------------- K1: turn_hidden via MFMA (K=384 GEMM + rank-1 bil term) ----------------
__global__ __launch_bounds__(128) void ca_hidden2(const float* __restrict__ te,
                                                  const float* __restrict__ bil,
                                                  const short* __restrict__ Wtb,
                                                  const float* __restrict__ wcol,
                                                  const float* __restrict__ bt,
                                                  float* __restrict__ h, short* __restrict__ hb,
                                                  int N) {
  const int t = threadIdx.x, lane = t & 63, w = t >> 6;
  const int g = lane >> 4, li = lane & 15;
  const int i0 = blockIdx.x * 32 + w * 16;
  f32x4 acc[4];
#pragma unroll
  for (int n = 0; n < 4; ++n) acc[n] = (f32x4){0.f, 0.f, 0.f, 0.f};
  const float* arow = te + (size_t)(i0 + li) * 384 + g * 8;
  for (int ks = 0; ks < 12; ++ks) {
    float4 a0 = *(const float4*)(arow + ks * 32);
    float4 a1 = *(const float4*)(arow + ks * 32 + 4);
    short8 af;
    af[0] = f2bf(a0.x); af[1] = f2bf(a0.y); af[2] = f2bf(a0.z); af[3] = f2bf(a0.w);
    af[4] = f2bf(a1.x); af[5] = f2bf(a1.y); af[6] = f2bf(a1.z); af[7] = f2bf(a1.w);
#pragma unroll
    for (int n = 0; n < 4; ++n) {
      short8 bf = *(const short8*)&Wtb[(size_t)(n * 16 + li) * 384 + ks * 32 + g * 8];
      acc[n] = __builtin_amdgcn_mfma_f32_16x16x32_bf16(af, bf, acc[n], 0, 0, 0);
    }
  }
#pragma unroll
  for (int n = 0; n < 4; ++n) {
    int col = n * 16 + li;
    float bb = bt[col], wc = wcol[col];
#pragma unroll
    for (int r = 0; r < 4; ++r) {
      int R = i0 + g * 4 + r;
      float val = acc[n][r] + bb + bil[R] * wc;
      h[(size_t)R * 64 + col] = val;
      hb[(size_t)R * 64 + col] = f2bf(val);
    }
  }
}

// ---------------- K2: q/k/v projections via MFMA ----------------
// q scaled by log2(e)/8 -> bf16 [N][64]; k -> bf16 [N][64]; v -> vt [64][N].
__global__ __launch_bounds__(128) void ca_qkv2(const short* __restrict__ hb,
    const short* __restrict__ Wqb, const float* __restrict__ bq,
    const short* __restrict__ Wkb, const float* __restrict__ bk2,
    const short* __restrict__ Wvb, const float* __restrict__ bv,
    short* __restrict__ qb, short* __restrict__ kb, short* __restrict__ vt, int N) {
  __shared__ short Vt[64][40];
  const int t = threadIdx.x, lane = t & 63, w = t >> 6;
  const int g = lane >> 4, li = lane & 15;
  const int ib = blockIdx.x * 32;
  const int i0 = ib + w * 16;
  short8 ha[2];
  ha[0] = *(const short8*)&hb[(size_t)(i0 + li) * 64 + g * 8];
  ha[1] = *(const short8*)&hb[(size_t)(i0 + li) * 64 + g * 8 + 32];
  const short* Wm[3] = {Wqb, Wkb, Wvb};
  const float* bm[3] = {bq, bk2, bv};
  const float QSC = 0.18033688011112042f;  // log2(e)/8
  for (int m = 0; m < 3; ++m) {
    f32x4 acc[4];
#pragma unroll
    for (int n = 0; n < 4; ++n) acc[n] = (f32x4){0.f, 0.f, 0.f, 0.f};
#pragma unroll
    for (int n = 0; n < 4; ++n)
#pragma unroll
      for (int ks = 0; ks < 2; ++ks) {
        short8 bf = *(const short8*)&Wm[m][(size_t)(n * 16 + li) * 64 + ks * 32 + g * 8];
        acc[n] = __builtin_amdgcn_mfma_f32_16x16x32_bf16(ha[ks], bf, acc[n], 0, 0, 0);
      }
    if (m == 0) {
#pragma unroll
      for (int n = 0; n < 4; ++n) {
        int col = n * 16 + li;
        float bb = bq[col];
#pragma unroll
        for (int r = 0; r < 4; ++r)
          qb[(size_t)(i0 + g * 4 + r) * 64 + col] = f2bf((acc[n][r] + bb) * QSC);
      }
    } else if (m == 1) {
#pragma unroll
      for (int n = 0; n < 4; ++n) {
        int col = n * 16 + li;
        float bb = bk2[col];
#pragma unroll
        for (int r = 0; r < 4; ++r)
          kb[(size_t)(i0 + g * 4 + r) * 64 + col] = f2bf(acc[n][r] + bb);
      }
    } else {
#pragma unroll
      for (int n = 0; n < 4; ++n) {
        int col = n * 16 + li;
        float bb = bv[col];
#pragma unroll
        for (int r = 0; r < 4; ++r)
          Vt[col][w * 16 + g * 4 + r] = f2bf(acc[n][r] + bb);
      }
    }
  }
  __syncthreads();
  const int c = t >> 1, half = t & 1;
  *(uint4*)&vt[(size_t)c * N + ib + half * 16] = *(uint4*)&Vt[c][half * 16];
  *(uint4*)&vt[(size_t)c * N + ib + half * 16 + 8] = *(uint4*)&Vt[c][half * 16 + 8];
}

// ---------------- K3: attention partials, no-max softmax, 8-way key split ----------------
// grid = (N/64 q-blocks) * 8 splits; block 256 = 4 waves; wave = 16 q rows x N/8 keys.
__global__ __launch_bounds__(256, 4) void ca_attn2(
    const short* __restrict__ qb, const short* __restrict__ kb, const short* __restrict__ vt,
    short* __restrict__ pO, float* __restrict__ pL, int N) {
  __shared__ short Pl[4][16][72];
  const int t = threadIdx.x, lane = t & 63, wid = t >> 6;
  const int g = lane >> 4, li = lane & 15;
  const int qblk = blockIdx.x >> 3, sp = blockIdx.x & 7;
  const int i0 = qblk * 64 + wid * 16;
  const int k0 = sp * (N >> 3);
  const int ntil = N >> 9;  // tiles of 64 keys in this split

  short8 qa[2];
  qa[0] = *(const short8*)&qb[(size_t)(i0 + li) * 64 + g * 8];
  qa[1] = *(const short8*)&qb[(size_t)(i0 + li) * 64 + g * 8 + 32];

  f32x4 acc[4], accs;
#pragma unroll
  for (int n = 0; n < 4; ++n) acc[n] = (f32x4){0.f, 0.f, 0.f, 0.f};
  accs = (f32x4){0.f, 0.f, 0.f, 0.f};

  const short onev = (li == 0) ? (short)0x3F80 : (short)0;
  short8 ones;
#pragma unroll
  for (int j = 0; j < 8; ++j) ones[j] = onev;

  for (int tt = 0; tt < ntil; ++tt) {
    const int j0 = k0 + tt * 64;
    f32x4 s4[4];
#pragma unroll
    for (int t4 = 0; t4 < 4; ++t4) s4[t4] = (f32x4){0.f, 0.f, 0.f, 0.f};
    short8 kf[4][2];
#pragma unroll
    for (int t4 = 0; t4 < 4; ++t4)
#pragma unroll
      for (int ks = 0; ks < 2; ++ks)
        kf[t4][ks] = *(const short8*)&kb[(size_t)(j0 + t4 * 16 + li) * 64 + g * 8 + ks * 32];
#pragma unroll
    for (int t4 = 0; t4 < 4; ++t4) {
      s4[t4] = __builtin_amdgcn_mfma_f32_16x16x32_bf16(qa[0], kf[t4][0], s4[t4], 0, 0, 0);
      s4[t4] = __builtin_amdgcn_mfma_f32_16x16x32_bf16(qa[1], kf[t4][1], s4[t4], 0, 0, 0);
    }
    // p = 2^s (q pre-scaled by log2e/8) -> bf16 (truncate) -> LDS
#pragma unroll
    for (int t4 = 0; t4 < 4; ++t4) {
#pragma unroll
      for (int r = 0; r < 4; ++r) {
        float pe;
        asm("v_exp_f32 %0, %1" : "=v"(pe) : "v"(s4[t4][r]));
        union { float f; unsigned u; } cv; cv.f = pe;
        Pl[wid][g * 4 + r][li + t4 * 16] = (short)(cv.u >> 16);
      }
    }
    asm volatile("s_waitcnt lgkmcnt(0)" ::: "memory");
#pragma unroll
    for (int ks2 = 0; ks2 < 2; ++ks2) {
      short8 pa = *(const short8*)&Pl[wid][li][g * 8 + ks2 * 32];
      accs = __builtin_amdgcn_mfma_f32_16x16x32_bf16(pa, ones, accs, 0, 0, 0);
#pragma unroll
      for (int dt = 0; dt < 4; ++dt) {
        short8 vf = *(const short8*)&vt[(size_t)(li + dt * 16) * N + j0 + ks2 * 32 + g * 8];
        acc[dt] = __builtin_amdgcn_mfma_f32_16x16x32_bf16(pa, vf, acc[dt], 0, 0, 0);
      }
    }
  }
  const size_t base = (size_t)sp * N + i0;
#pragma unroll
  for (int dt = 0; dt < 4; ++dt)
#pragma unroll
    for (int r = 0; r < 4; ++r)
      pO[(base + g * 4 + r) * 64 + li + dt * 16] = f2bf(acc[dt][r]);
  if (li == 0) {
#pragma unroll
    for (int r = 0; r < 4; ++r) pL[(size_t)sp * N + i0 + g * 4 + r] = accs[r];
  }
}

// ---------------- K4: merge 8 splits + residual + cross-attn + score + gate ----------------
__global__ __launch_bounds__(256) void ca_merge(
    const float* __restrict__ h, const short* __restrict__ pO, const float* __restrict__ pL,
    const float* __restrict__ u_ws, const float* __restrict__ scal,
    const float* __restrict__ bil, const float* __restrict__ Wsc,
    const float* __restrict__ bsc_p, const float* __restrict__ rgate_p,
    float* __restrict__ out, int N) {
  const int t = threadIdx.x;
  const int row = blockIdx.x * 32 + (t >> 3), e = t & 7, d0 = e * 8;
  float L = 0.f;
#pragma unroll
  for (int sp = 0; sp < 8; ++sp) L += pL[(size_t)sp * N + row];
  float o[8];
#pragma unroll
  for (int i = 0; i < 8; ++i) o[i] = 0.f;
#pragma unroll
  for (int sp = 0; sp < 8; ++sp) {
    short8 ov = *(const short8*)&pO[((size_t)sp * N + row) * 64 + d0];
#pragma unroll
    for (int i = 0; i < 8; ++i) o[i] += bf2f(ov[i]);
  }
  const float invL = 1.f / L;
  float s1 = 0.f, s2 = 0.f;
#pragma unroll
  for (int i = 0; i < 8; ++i) {
    float h2 = h[(size_t)row * 64 + d0 + i] + o[i] * invL;
    s1 += h2 * u_ws[d0 + i];
    s2 += h2 * Wsc[d0 + i];
  }
#pragma unroll
  for (int mask = 1; mask < 8; mask <<= 1) {
    s1 += __shfl_xor(s1, mask, 64);
    s2 += __shfl_xor(s2, mask, 64);
  }
  if (e == 0) {
    float gate = 1.f / (1.f + __expf(-rgate_p[0]));
    float caw = 1.f / (1.f + __expf(-(s1 + scal[0]) * 0.125f));
    float score = s2 + caw * scal[1] + bsc_p[0];
    out[row] = (1.f - gate) * bil[row] + gate * score;
  }
}

extern "C" void kernel_launch(void* const* d_in, const int* in_sizes, int n_in,
                              void* d_out, int out_size, void* d_ws, size_t ws_size,
                              hipStream_t stream) {
  const float* sit  = (const float*)d_in[0];
  const float* te   = (const float*)d_in[1];
  const float* bil  = (const float*)d_in[2];
  const float* Wt   = (const float*)d_in[3];
  const float* bt   = (const float*)d_in[4];
  const float* Ws   = (const float*)d_in[5];
  const float* bs   = (const float*)d_in[6];
  const float* Wsaq = (const float*)d_in[7];
  const float* bsaq = (const float*)d_in[8];
  const float* Wsak = (const float*)d_in[9];
  const float* bsak = (const float*)d_in[10];
  const float* Wsav = (const float*)d_in[11];
  const float* bsav = (const float*)d_in[12];
  const float* Wcq  = (const float*)d_in[13];
  const float* bcq  = (const float*)d_in[14];
  const float* Wck  = (const float*)d_in[15];
  const float* bck  = (const float*)d_in[16];
  const float* Wcv  = (const float*)d_in[17];
  const float* bcv  = (const float*)d_in[18];
  const float* Wsc  = (const float*)d_in[19];
  const float* bsc  = (const float*)d_in[20];
  const float* rgate= (const float*)d_in[21];
  const int N = in_sizes[2];

  char* w = (char*)d_ws;
  size_t off = 0;
  float* h     = (float*)(w + off); off += (size_t)N * 64 * 4;
  short* hbuf  = (short*)(w + off); off += (size_t)N * 64 * 2;
  short* qbuf  = (short*)(w + off); off += (size_t)N * 64 * 2;
  short* kbuf  = (short*)(w + off); off += (size_t)N * 64 * 2;
  short* vtbuf = (short*)(w + off); off += (size_t)N * 64 * 2;
  float* u_ws  = (float*)(w + off); off += 64 * 4;
  float* scal  = (float*)(w + off); off += 4 * 4;
  short* Wtb   = (short*)(w + off); off += 24576 * 2;
  float* wcol  = (float*)(w + off); off += 64 * 4;
  short* Wqb   = (short*)(w + off); off += 4096 * 2;
  short* Wkb   = (short*)(w + off); off += 4096 * 2;
  short* Wvb   = (short*)(w + off); off += 4096 * 2;
  short* pO    = (short*)(w + off); off += (size_t)8 * N * 64 * 2;
  float* pL    = (float*)(w + off); off += (size_t)8 * N * 4;

  ca_pre<<<1, 256, 0, stream>>>(sit, Ws, bs, Wck, bck, Wcv, bcv, Wcq, bcq, Wsc, u_ws, scal);
  ca_conv<<<145, 256, 0, stream>>>(Wt, Wsaq, Wsak, Wsav, Wtb, wcol, Wqb, Wkb, Wvb);
  ca_hidden2<<<N / 32, 128, 0, stream>>>(te, bil, Wtb, wcol, bt, h, hbuf, N);
  ca_qkv2<<<N / 32, 128, 0, stream>>>(hbuf, Wqb, bsaq, Wkb, bsak, Wvb, bsav,
                                      qbuf, kbuf, vtbuf, N);
  ca_attn2<<<N / 8, 256, 0, stream>>>(qbuf, kbuf, vtbuf, pO, pL, N);
  ca_merge<<<N / 32, 256, 0, stream>>>(h, pO, pL, u_ws, scal, bil, Wsc, bsc, rgate,
                                       (float*)d_out, N);
}

// Round 4
// 72.265 us; speedup vs baseline: 5.1125x; 2.1793x over previous
//
#include <hip/hip_runtime.h>
#include <hip/hip_bf16.h>

typedef __attribute__((ext_vector_type(8))) short short8;
typedef __attribute__((ext_vector_type(4))) float f32x4;

__device__ __forceinline__ short f2bf(float x) {
  union { float f; unsigned u; } a; a.f = x;
  unsigned r = (a.u + 0x7FFFu + ((a.u >> 16) & 1u)) >> 16;
  return (short)r;
}
__device__ __forceinline__ float bf2f(short x) {
  union { unsigned u; float f; } a; a.u = ((unsigned)(unsigned short)x) << 16;
  return a.f;
}
__device__ __forceinline__ void gload16(const void* g, void* l) {
  __builtin_amdgcn_global_load_lds((const __attribute__((address_space(1))) unsigned int*)g,
                                   (__attribute__((address_space(3))) unsigned int*)l, 16, 0, 0);
}

// ---------------- K0: small precompute (situation path) ----------------
__global__ void ca_pre(const float* __restrict__ sit, const float* __restrict__ Ws,
                       const float* __restrict__ bs, const float* __restrict__ Wck,
                       const float* __restrict__ bck, const float* __restrict__ Wcv,
                       const float* __restrict__ bcv, const float* __restrict__ Wcq,
                       const float* __restrict__ bcq, const float* __restrict__ Wsc,
                       float* __restrict__ u_ws, float* __restrict__ scal) {
  __shared__ float part[4][64];
  __shared__ float sh[64], ck[64], cv[64];
  int t = threadIdx.x;
  int j = t & 63, p = t >> 6;
  float a = 0.f;
  for (int d = p * 96; d < p * 96 + 96; ++d) a += Ws[j * 384 + d] * sit[d];
  part[p][j] = a;
  __syncthreads();
  if (t < 64) sh[t] = part[0][t] + part[1][t] + part[2][t] + part[3][t] + bs[t];
  __syncthreads();
  if (t < 64) {
    float kk = bck[t], vv = bcv[t];
    for (int d = 0; d < 64; ++d) { kk += Wck[t * 64 + d] * sh[d]; vv += Wcv[t * 64 + d] * sh[d]; }
    ck[t] = kk; cv[t] = vv;
  }
  __syncthreads();
  if (t < 64) {
    float uu = 0.f;
    for (int jj = 0; jj < 64; ++jj) uu += Wcq[jj * 64 + t] * ck[jj];
    u_ws[t] = uu;
  }
  if (t == 0) {
    float c0 = 0.f, cw = 0.f;
    for (int jj = 0; jj < 64; ++jj) { c0 += bcq[jj] * ck[jj]; cw += cv[jj] * Wsc[jj]; }
    scal[0] = c0; scal[1] = cw;
  }
}

// ---------------- K0b: weight conversion to bf16 ----------------
__global__ __launch_bounds__(256) void ca_conv(const float* __restrict__ Wt,
    const float* __restrict__ Wsaq, const float* __restrict__ Wsak, const float* __restrict__ Wsav,
    short* __restrict__ Wtb, float* __restrict__ wcol,
    short* __restrict__ Wqb, short* __restrict__ Wkb, short* __restrict__ Wvb) {
  int idx = blockIdx.x * 256 + threadIdx.x;
  if (idx < 24576) {
    int r = idx / 384, c = idx % 384;
    Wtb[idx] = f2bf(Wt[r * 385 + c]);
  } else if (idx < 24640) {
    wcol[idx - 24576] = Wt[(idx - 24576) * 385 + 384];
  } else if (idx < 28736) {
    Wqb[idx - 24640] = f2bf(Wsaq[idx - 24640]);
  } else if (idx < 32832) {
    Wkb[idx - 28736] = f2bf(Wsak[idx - 28736]);
  } else if (idx < 36928) {
    Wvb[idx - 32832] = f2bf(Wsav[idx - 32832]);
  }
}

// ---------------- K1: turn_hidden via MFMA (K=384 GEMM + rank-1 bil term) ----------------
__global__ __launch_bounds__(128) void ca_hidden2(const float* __restrict__ te,
                                                  const float* __restrict__ bil,
                                                  const short* __restrict__ Wtb,
                                                  const float* __restrict__ wcol,
                                                  const float* __restrict__ bt,
                                                  float* __restrict__ h, short* __restrict__ hb,
                                                  int N) {
  const int t = threadIdx.x, lane = t & 63, w = t >> 6;
  const int g = lane >> 4, li = lane & 15;
  const int i0 = blockIdx.x * 32 + w * 16;
  f32x4 acc[4];
#pragma unroll
  for (int n = 0; n < 4; ++n) acc[n] = (f32x4){0.f, 0.f, 0.f, 0.f};
  const float* arow = te + (size_t)(i0 + li) * 384 + g * 8;
  for (int ks = 0; ks < 12; ++ks) {
    float4 a0 = *(const float4*)(arow + ks * 32);
    float4 a1 = *(const float4*)(arow + ks * 32 + 4);
    short8 af;
    af[0] = f2bf(a0.x); af[1] = f2bf(a0.y); af[2] = f2bf(a0.z); af[3] = f2bf(a0.w);
    af[4] = f2bf(a1.x); af[5] = f2bf(a1.y); af[6] = f2bf(a1.z); af[7] = f2bf(a1.w);
#pragma unroll
    for (int n = 0; n < 4; ++n) {
      short8 bf = *(const short8*)&Wtb[(size_t)(n * 16 + li) * 384 + ks * 32 + g * 8];
      acc[n] = __builtin_amdgcn_mfma_f32_16x16x32_bf16(af, bf, acc[n], 0, 0, 0);
    }
  }
#pragma unroll
  for (int n = 0; n < 4; ++n) {
    int col = n * 16 + li;
    float bb = bt[col], wc = wcol[col];
#pragma unroll
    for (int r = 0; r < 4; ++r) {
      int R = i0 + g * 4 + r;
      float val = acc[n][r] + bb + bil[R] * wc;
      h[(size_t)R * 64 + col] = val;
      hb[(size_t)R * 64 + col] = f2bf(val);
    }
  }
}

// ---------------- K2: q/k/v projections via MFMA ----------------
__global__ __launch_bounds__(128) void ca_qkv2(const short* __restrict__ hb,
    const short* __restrict__ Wqb, const float* __restrict__ bq,
    const short* __restrict__ Wkb, const float* __restrict__ bk2,
    const short* __restrict__ Wvb, const float* __restrict__ bv,
    short* __restrict__ qb, short* __restrict__ kb, short* __restrict__ vt, int N) {
  __shared__ short Vt[64][40];
  const int t = threadIdx.x, lane = t & 63, w = t >> 6;
  const int g = lane >> 4, li = lane & 15;
  const int ib = blockIdx.x * 32;
  const int i0 = ib + w * 16;
  short8 ha[2];
  ha[0] = *(const short8*)&hb[(size_t)(i0 + li) * 64 + g * 8];
  ha[1] = *(const short8*)&hb[(size_t)(i0 + li) * 64 + g * 8 + 32];
  const short* Wm[3] = {Wqb, Wkb, Wvb};
  const float* bm[3] = {bq, bk2, bv};
  const float QSC = 0.18033688011112042f;  // log2(e)/8
  for (int m = 0; m < 3; ++m) {
    f32x4 acc[4];
#pragma unroll
    for (int n = 0; n < 4; ++n) acc[n] = (f32x4){0.f, 0.f, 0.f, 0.f};
#pragma unroll
    for (int n = 0; n < 4; ++n)
#pragma unroll
      for (int ks = 0; ks < 2; ++ks) {
        short8 bf = *(const short8*)&Wm[m][(size_t)(n * 16 + li) * 64 + ks * 32 + g * 8];
        acc[n] = __builtin_amdgcn_mfma_f32_16x16x32_bf16(ha[ks], bf, acc[n], 0, 0, 0);
      }
    if (m == 0) {
#pragma unroll
      for (int n = 0; n < 4; ++n) {
        int col = n * 16 + li;
        float bb = bq[col];
#pragma unroll
        for (int r = 0; r < 4; ++r)
          qb[(size_t)(i0 + g * 4 + r) * 64 + col] = f2bf((acc[n][r] + bb) * QSC);
      }
    } else if (m == 1) {
#pragma unroll
      for (int n = 0; n < 4; ++n) {
        int col = n * 16 + li;
        float bb = bk2[col];
#pragma unroll
        for (int r = 0; r < 4; ++r)
          kb[(size_t)(i0 + g * 4 + r) * 64 + col] = f2bf(acc[n][r] + bb);
      }
    } else {
#pragma unroll
      for (int n = 0; n < 4; ++n) {
        int col = n * 16 + li;
        float bb = bv[col];
#pragma unroll
        for (int r = 0; r < 4; ++r)
          Vt[col][w * 16 + g * 4 + r] = f2bf(acc[n][r] + bb);
      }
    }
  }
  __syncthreads();
  const int c = t >> 1, half = t & 1;
  *(uint4*)&vt[(size_t)c * N + ib + half * 16] = *(uint4*)&Vt[c][half * 16];
  *(uint4*)&vt[(size_t)c * N + ib + half * 16 + 8] = *(uint4*)&Vt[c][half * 16 + 8];
}

// ---------------- K3: LDS-staged attention partials, no-max softmax, 8-way key split ----------------
// 512 blocks = 64 qblk x 8 sp (mapped so same-CU blocks share sp). Block = 4 waves x 32 q-rows.
// K,V tiles (64 keys) double-buffered in LDS in fragment-linear layout via global_load_lds.
__global__ __launch_bounds__(256, 2) void ca_attn3(
    const short* __restrict__ qb, const short* __restrict__ kb, const short* __restrict__ vt,
    short* __restrict__ pO, float* __restrict__ pL, int N) {
  __shared__ short Kl[2][4096];   // [buf][chunk(t4*2+ks)*512 + lane*8]
  __shared__ short Vl[2][4096];   // [buf][chunk(ks2*4+dt)*512 + lane*8]
  __shared__ short Pl[4][32][72];
  const int t = threadIdx.x, lane = t & 63, wid = t >> 6;
  const int g = lane >> 4, li = lane & 15;
  const int bid = blockIdx.x;
  const int sp = (bid >> 1) & 7;                 // same-CU blocks (b, b+256) share sp
  const int qblk = (bid >> 4) * 2 + (bid & 1);
  const int i0 = qblk * 128 + wid * 32;
  const int k0 = sp * (N >> 3);
  const int ntil = N >> 9;  // 16 tiles of 64 keys

  // stage source bases (wave stages K chunks {2w,2w+1}, V chunks {2w,2w+1})
  const short* ksrc = kb + ((size_t)(wid * 16 + li)) * 64 + g * 8;       // + j0*64 (+32 for ks=1)
  const short* vsrc0 = vt + (size_t)(li + ((2 * wid) & 3) * 16) * N + (wid >> 1) * 32 + g * 8;
  const short* vsrc1 = vt + (size_t)(li + ((2 * wid + 1) & 3) * 16) * N + (wid >> 1) * 32 + g * 8;

#define STAGE_TILE(b, j0)                                                \
  do {                                                                   \
    gload16(ksrc + (size_t)(j0) * 64,       &Kl[b][(2 * wid) * 512]);    \
    gload16(ksrc + (size_t)(j0) * 64 + 32,  &Kl[b][(2 * wid + 1) * 512]);\
    gload16(vsrc0 + (j0),                   &Vl[b][(2 * wid) * 512]);    \
    gload16(vsrc1 + (j0),                   &Vl[b][(2 * wid + 1) * 512]);\
  } while (0)

  short8 qa[2][2];
#pragma unroll
  for (int qs = 0; qs < 2; ++qs)
#pragma unroll
    for (int ks = 0; ks < 2; ++ks)
      qa[qs][ks] = *(const short8*)&qb[(size_t)(i0 + qs * 16 + li) * 64 + g * 8 + ks * 32];

  f32x4 acc[2][4], accs[2];
#pragma unroll
  for (int qs = 0; qs < 2; ++qs) {
#pragma unroll
    for (int n = 0; n < 4; ++n) acc[qs][n] = (f32x4){0.f, 0.f, 0.f, 0.f};
    accs[qs] = (f32x4){0.f, 0.f, 0.f, 0.f};
  }
  const short onev = (li == 0) ? (short)0x3F80 : (short)0;
  short8 ones;
#pragma unroll
  for (int j = 0; j < 8; ++j) ones[j] = onev;

  // prologue: stage tile 0
  STAGE_TILE(0, k0);
  asm volatile("s_waitcnt vmcnt(0)" ::: "memory");

  for (int tt = 0; tt < ntil; ++tt) {
    const int cur = tt & 1;
    __builtin_amdgcn_s_barrier();     // all waves done reading buf[cur^1]; stage tt arrived
    if (tt + 1 < ntil) STAGE_TILE(cur ^ 1, k0 + (tt + 1) * 64);

    // ---- QK^T from LDS ----
    f32x4 s4[2][4];
#pragma unroll
    for (int qs = 0; qs < 2; ++qs)
#pragma unroll
      for (int t4 = 0; t4 < 4; ++t4) s4[qs][t4] = (f32x4){0.f, 0.f, 0.f, 0.f};
    __builtin_amdgcn_s_setprio(1);
#pragma unroll
    for (int ks = 0; ks < 2; ++ks)
#pragma unroll
      for (int t4 = 0; t4 < 4; ++t4) {
        short8 kf = *(const short8*)&Kl[cur][(t4 * 2 + ks) * 512 + lane * 8];
        s4[0][t4] = __builtin_amdgcn_mfma_f32_16x16x32_bf16(qa[0][ks], kf, s4[0][t4], 0, 0, 0);
        s4[1][t4] = __builtin_amdgcn_mfma_f32_16x16x32_bf16(qa[1][ks], kf, s4[1][t4], 0, 0, 0);
      }
    __builtin_amdgcn_s_setprio(0);
    // ---- p = 2^s -> bf16 -> Pl ----
#pragma unroll
    for (int qs = 0; qs < 2; ++qs)
#pragma unroll
      for (int t4 = 0; t4 < 4; ++t4)
#pragma unroll
        for (int r = 0; r < 4; ++r) {
          float pe;
          asm("v_exp_f32 %0, %1" : "=v"(pe) : "v"(s4[qs][t4][r]));
          union { float f; unsigned u; } cv; cv.f = pe;
          Pl[wid][qs * 16 + g * 4 + r][li + t4 * 16] = (short)(cv.u >> 16);
        }
    asm volatile("s_waitcnt lgkmcnt(0)" ::: "memory");
    // ---- PV + row-sum from LDS ----
    short8 pa[2][2];
#pragma unroll
    for (int qs = 0; qs < 2; ++qs)
#pragma unroll
      for (int ks2 = 0; ks2 < 2; ++ks2)
        pa[qs][ks2] = *(const short8*)&Pl[wid][qs * 16 + li][g * 8 + ks2 * 32];
    __builtin_amdgcn_s_setprio(1);
#pragma unroll
    for (int ks2 = 0; ks2 < 2; ++ks2) {
      accs[0] = __builtin_amdgcn_mfma_f32_16x16x32_bf16(pa[0][ks2], ones, accs[0], 0, 0, 0);
      accs[1] = __builtin_amdgcn_mfma_f32_16x16x32_bf16(pa[1][ks2], ones, accs[1], 0, 0, 0);
#pragma unroll
      for (int dt = 0; dt < 4; ++dt) {
        short8 vf = *(const short8*)&Vl[cur][(ks2 * 4 + dt) * 512 + lane * 8];
        acc[0][dt] = __builtin_amdgcn_mfma_f32_16x16x32_bf16(pa[0][ks2], vf, acc[0][dt], 0, 0, 0);
        acc[1][dt] = __builtin_amdgcn_mfma_f32_16x16x32_bf16(pa[1][ks2], vf, acc[1][dt], 0, 0, 0);
      }
    }
    __builtin_amdgcn_s_setprio(0);
    asm volatile("s_waitcnt vmcnt(0)" ::: "memory");  // own stage loads for tt+1 landed
  }

  const size_t base = (size_t)sp * N + i0;
#pragma unroll
  for (int qs = 0; qs < 2; ++qs) {
#pragma unroll
    for (int dt = 0; dt < 4; ++dt)
#pragma unroll
      for (int r = 0; r < 4; ++r)
        pO[(base + qs * 16 + g * 4 + r) * 64 + li + dt * 16] = f2bf(acc[qs][dt][r]);
    if (li == 0) {
#pragma unroll
      for (int r = 0; r < 4; ++r)
        pL[(size_t)sp * N + i0 + qs * 16 + g * 4 + r] = accs[qs][r];
    }
  }
#undef STAGE_TILE
}

// ---------------- K4: merge 8 splits + residual + cross-attn + score + gate ----------------
__global__ __launch_bounds__(256) void ca_merge(
    const float* __restrict__ h, const short* __restrict__ pO, const float* __restrict__ pL,
    const float* __restrict__ u_ws, const float* __restrict__ scal,
    const float* __restrict__ bil, const float* __restrict__ Wsc,
    const float* __restrict__ bsc_p, const float* __restrict__ rgate_p,
    float* __restrict__ out, int N) {
  const int t = threadIdx.x;
  const int row = blockIdx.x * 32 + (t >> 3), e = t & 7, d0 = e * 8;
  float L = 0.f;
#pragma unroll
  for (int sp = 0; sp < 8; ++sp) L += pL[(size_t)sp * N + row];
  float o[8];
#pragma unroll
  for (int i = 0; i < 8; ++i) o[i] = 0.f;
#pragma unroll
  for (int sp = 0; sp < 8; ++sp) {
    short8 ov = *(const short8*)&pO[((size_t)sp * N + row) * 64 + d0];
#pragma unroll
    for (int i = 0; i < 8; ++i) o[i] += bf2f(ov[i]);
  }
  const float invL = 1.f / L;
  float s1 = 0.f, s2 = 0.f;
#pragma unroll
  for (int i = 0; i < 8; ++i) {
    float h2 = h[(size_t)row * 64 + d0 + i] + o[i] * invL;
    s1 += h2 * u_ws[d0 + i];
    s2 += h2 * Wsc[d0 + i];
  }
#pragma unroll
  for (int mask = 1; mask < 8; mask <<= 1) {
    s1 += __shfl_xor(s1, mask, 64);
    s2 += __shfl_xor(s2, mask, 64);
  }
  if (e == 0) {
    float gate = 1.f / (1.f + __expf(-rgate_p[0]));
    float caw = 1.f / (1.f + __expf(-(s1 + scal[0]) * 0.125f));
    float score = s2 + caw * scal[1] + bsc_p[0];
    out[row] = (1.f - gate) * bil[row] + gate * score;
  }
}

extern "C" void kernel_launch(void* const* d_in, const int* in_sizes, int n_in,
                              void* d_out, int out_size, void* d_ws, size_t ws_size,
                              hipStream_t stream) {
  const float* sit  = (const float*)d_in[0];
  const float* te   = (const float*)d_in[1];
  const float* bil  = (const float*)d_in[2];
  const float* Wt   = (const float*)d_in[3];
  const float* bt   = (const float*)d_in[4];
  const float* Ws   = (const float*)d_in[5];
  const float* bs   = (const float*)d_in[6];
  const float* Wsaq = (const float*)d_in[7];
  const float* bsaq = (const float*)d_in[8];
  const float* Wsak = (const float*)d_in[9];
  const float* bsak = (const float*)d_in[10];
  const float* Wsav = (const float*)d_in[11];
  const float* bsav = (const float*)d_in[12];
  const float* Wcq  = (const float*)d_in[13];
  const float* bcq  = (const float*)d_in[14];
  const float* Wck  = (const float*)d_in[15];
  const float* bck  = (const float*)d_in[16];
  const float* Wcv  = (const float*)d_in[17];
  const float* bcv  = (const float*)d_in[18];
  const float* Wsc  = (const float*)d_in[19];
  const float* bsc  = (const float*)d_in[20];
  const float* rgate= (const float*)d_in[21];
  const int N = in_sizes[2];

  char* w = (char*)d_ws;
  size_t off = 0;
  float* h     = (float*)(w + off); off += (size_t)N * 64 * 4;
  short* hbuf  = (short*)(w + off); off += (size_t)N * 64 * 2;
  short* qbuf  = (short*)(w + off); off += (size_t)N * 64 * 2;
  short* kbuf  = (short*)(w + off); off += (size_t)N * 64 * 2;
  short* vtbuf = (short*)(w + off); off += (size_t)N * 64 * 2;
  float* u_ws  = (float*)(w + off); off += 64 * 4;
  float* scal  = (float*)(w + off); off += 4 * 4;
  short* Wtb   = (short*)(w + off); off += 24576 * 2;
  float* wcol  = (float*)(w + off); off += 64 * 4;
  short* Wqb   = (short*)(w + off); off += 4096 * 2;
  short* Wkb   = (short*)(w + off); off += 4096 * 2;
  short* Wvb   = (short*)(w + off); off += 4096 * 2;
  short* pO    = (short*)(w + off); off += (size_t)8 * N * 64 * 2;
  float* pL    = (float*)(w + off); off += (size_t)8 * N * 4;

  ca_pre<<<1, 256, 0, stream>>>(sit, Ws, bs, Wck, bck, Wcv, bcv, Wcq, bcq, Wsc, u_ws, scal);
  ca_conv<<<145, 256, 0, stream>>>(Wt, Wsaq, Wsak, Wsav, Wtb, wcol, Wqb, Wkb, Wvb);
  ca_hidden2<<<N / 32, 128, 0, stream>>>(te, bil, Wtb, wcol, bt, h, hbuf, N);
  ca_qkv2<<<N / 32, 128, 0, stream>>>(hbuf, Wqb, bsaq, Wkb, bsak, Wvb, bsav,
                                      qbuf, kbuf, vtbuf, N);
  ca_attn3<<<N / 16, 256, 0, stream>>>(qbuf, kbuf, vtbuf, pO, pL, N);
  ca_merge<<<N / 32, 256, 0, stream>>>(h, pO, pL, u_ws, scal, bil, Wsc, bsc, rgate,
                                       (float*)d_out, N);
}

// Round 5
// 64.519 us; speedup vs baseline: 5.7262x; 1.1201x over previous
//
#include <hip/hip_runtime.h>
#include <hip/hip_bf16.h>

typedef __attribute__((ext_vector_type(8))) short short8;
typedef __attribute__((ext_vector_type(4))) float f32x4;

__device__ __forceinline__ short f2bf(float x) {
  union { float f; unsigned u; } a; a.f = x;
  unsigned r = (a.u + 0x7FFFu + ((a.u >> 16) & 1u)) >> 16;
  return (short)r;
}
__device__ __forceinline__ float bf2f(short x) {
  union { unsigned u; float f; } a; a.u = ((unsigned)(unsigned short)x) << 16;
  return a.f;
}
__device__ __forceinline__ void gload16(const void* g, void* l) {
  __builtin_amdgcn_global_load_lds((const __attribute__((address_space(1))) unsigned int*)g,
                                   (__attribute__((address_space(3))) unsigned int*)l, 16, 0, 0);
}

// ---------------- K0: setup = weight conversion (blocks 0..144) + situation path (block 145) ----
__global__ __launch_bounds__(256) void ca_setup(
    const float* __restrict__ Wt, const float* __restrict__ Wsaq, const float* __restrict__ Wsak,
    const float* __restrict__ Wsav, short* __restrict__ Wtb, float* __restrict__ wcol,
    short* __restrict__ Wqb, short* __restrict__ Wkb, short* __restrict__ Wvb,
    const float* __restrict__ sit, const float* __restrict__ Ws, const float* __restrict__ bs,
    const float* __restrict__ Wck, const float* __restrict__ bck, const float* __restrict__ Wcv,
    const float* __restrict__ bcv, const float* __restrict__ Wcq, const float* __restrict__ bcq,
    const float* __restrict__ Wsc, float* __restrict__ u_ws, float* __restrict__ scal) {
  const int bid = blockIdx.x, t = threadIdx.x;
  if (bid < 145) {
    int idx = bid * 256 + t;
    if (idx < 24576) {
      int r = idx / 384, c = idx % 384;
      Wtb[idx] = f2bf(Wt[r * 385 + c]);
    } else if (idx < 24640) {
      wcol[idx - 24576] = Wt[(idx - 24576) * 385 + 384];
    } else if (idx < 28736) {
      Wqb[idx - 24640] = f2bf(Wsaq[idx - 24640]);
    } else if (idx < 32832) {
      Wkb[idx - 28736] = f2bf(Wsak[idx - 28736]);
    } else if (idx < 36928) {
      Wvb[idx - 32832] = f2bf(Wsav[idx - 32832]);
    }
    return;
  }
  // situation path
  __shared__ float part[4][64];
  __shared__ float sh[64], ck[64], cv[64];
  int j = t & 63, p = t >> 6;
  float a = 0.f;
  for (int d = p * 96; d < p * 96 + 96; ++d) a += Ws[j * 384 + d] * sit[d];
  part[p][j] = a;
  __syncthreads();
  if (t < 64) sh[t] = part[0][t] + part[1][t] + part[2][t] + part[3][t] + bs[t];
  __syncthreads();
  if (t < 64) {
    float kk = bck[t], vv = bcv[t];
    for (int d = 0; d < 64; ++d) { kk += Wck[t * 64 + d] * sh[d]; vv += Wcv[t * 64 + d] * sh[d]; }
    ck[t] = kk; cv[t] = vv;
  }
  __syncthreads();
  if (t < 64) {
    float uu = 0.f;
    for (int jj = 0; jj < 64; ++jj) uu += Wcq[jj * 64 + t] * ck[jj];
    u_ws[t] = uu;
  }
  if (t == 0) {
    float c0 = 0.f, cw = 0.f;
    for (int jj = 0; jj < 64; ++jj) { c0 += bcq[jj] * ck[jj]; cw += cv[jj] * Wsc[jj]; }
    scal[0] = c0; scal[1] = cw;
  }
}

// ---------------- K1: fused projections: hidden (K=384 + rank-1) then q/k/v ----------------
// grid N/64, block 256 = 4 waves; wave w owns rows i0+16w..+15.
__global__ __launch_bounds__(256) void ca_proj(
    const float* __restrict__ te, const float* __restrict__ bil,
    const short* __restrict__ Wtb, const float* __restrict__ wcol, const float* __restrict__ bt,
    const short* __restrict__ Wqb, const float* __restrict__ bq,
    const short* __restrict__ Wkb, const float* __restrict__ bk2,
    const short* __restrict__ Wvb, const float* __restrict__ bv,
    short* __restrict__ hb, short* __restrict__ qb, short* __restrict__ kb,
    short* __restrict__ vt, int N) {
  __shared__ short Hl[64][72];
  __shared__ short Vt[64][72];
  const int t = threadIdx.x, lane = t & 63, w = t >> 6;
  const int g = lane >> 4, li = lane & 15;
  const int i0 = blockIdx.x * 64;
  const int rw = i0 + w * 16;

  // ---- phase A: turn_hidden ----
  f32x4 acc[4];
#pragma unroll
  for (int n = 0; n < 4; ++n) acc[n] = (f32x4){0.f, 0.f, 0.f, 0.f};
  const float* arow = te + (size_t)(rw + li) * 384 + g * 8;
  for (int ks = 0; ks < 12; ++ks) {
    float4 a0 = *(const float4*)(arow + ks * 32);
    float4 a1 = *(const float4*)(arow + ks * 32 + 4);
    short8 af;
    af[0] = f2bf(a0.x); af[1] = f2bf(a0.y); af[2] = f2bf(a0.z); af[3] = f2bf(a0.w);
    af[4] = f2bf(a1.x); af[5] = f2bf(a1.y); af[6] = f2bf(a1.z); af[7] = f2bf(a1.w);
#pragma unroll
    for (int n = 0; n < 4; ++n) {
      short8 bf = *(const short8*)&Wtb[(size_t)(n * 16 + li) * 384 + ks * 32 + g * 8];
      acc[n] = __builtin_amdgcn_mfma_f32_16x16x32_bf16(af, bf, acc[n], 0, 0, 0);
    }
  }
#pragma unroll
  for (int n = 0; n < 4; ++n) {
    int col = n * 16 + li;
    float bb = bt[col], wc = wcol[col];
#pragma unroll
    for (int r = 0; r < 4; ++r) {
      int R = rw + g * 4 + r;
      Hl[w * 16 + g * 4 + r][col] = f2bf(acc[n][r] + bb + bil[R] * wc);
    }
  }
  __syncthreads();
  // vectorized hb write
  {
    int row = t >> 2, seg = t & 3;
    *(uint4*)&hb[(size_t)(i0 + row) * 64 + seg * 16] = *(uint4*)&Hl[row][seg * 16];
    *(uint4*)&hb[(size_t)(i0 + row) * 64 + seg * 16 + 8] = *(uint4*)&Hl[row][seg * 16 + 8];
  }
  // ---- phase B: q/k/v ----
  short8 ha[2];
  ha[0] = *(const short8*)&Hl[w * 16 + li][g * 8];
  ha[1] = *(const short8*)&Hl[w * 16 + li][g * 8 + 32];
  const short* Wm[3] = {Wqb, Wkb, Wvb};
  const float* bm[3] = {bq, bk2, bv};
  const float QSC = 0.18033688011112042f;  // log2(e)/8
#pragma unroll
  for (int m = 0; m < 3; ++m) {
    f32x4 pacc[4];
#pragma unroll
    for (int n = 0; n < 4; ++n) pacc[n] = (f32x4){0.f, 0.f, 0.f, 0.f};
#pragma unroll
    for (int n = 0; n < 4; ++n)
#pragma unroll
      for (int ks = 0; ks < 2; ++ks) {
        short8 bf = *(const short8*)&Wm[m][(size_t)(n * 16 + li) * 64 + ks * 32 + g * 8];
        pacc[n] = __builtin_amdgcn_mfma_f32_16x16x32_bf16(ha[ks], bf, pacc[n], 0, 0, 0);
      }
    if (m == 0) {
#pragma unroll
      for (int n = 0; n < 4; ++n) {
        int col = n * 16 + li;
        float bb = bq[col];
#pragma unroll
        for (int r = 0; r < 4; ++r)
          qb[(size_t)(rw + g * 4 + r) * 64 + col] = f2bf((pacc[n][r] + bb) * QSC);
      }
    } else if (m == 1) {
#pragma unroll
      for (int n = 0; n < 4; ++n) {
        int col = n * 16 + li;
        float bb = bk2[col];
#pragma unroll
        for (int r = 0; r < 4; ++r)
          kb[(size_t)(rw + g * 4 + r) * 64 + col] = f2bf(pacc[n][r] + bb);
      }
    } else {
#pragma unroll
      for (int n = 0; n < 4; ++n) {
        int col = n * 16 + li;
        float bb = bv[col];
#pragma unroll
        for (int r = 0; r < 4; ++r)
          Vt[col][w * 16 + g * 4 + r] = f2bf(pacc[n][r] + bb);
      }
    }
  }
  __syncthreads();
  // vectorized vt write (transposed): block covers cols i0..i0+63 of all 64 vt rows
  {
    int c = t >> 2, seg = t & 3;
    *(uint4*)&vt[(size_t)c * N + i0 + seg * 16] = *(uint4*)&Vt[c][seg * 16];
    *(uint4*)&vt[(size_t)c * N + i0 + seg * 16 + 8] = *(uint4*)&Vt[c][seg * 16 + 8];
  }
}

// ---------------- K2: LDS-staged attention partials, no-max softmax, 8-way key split ----------------
__global__ __launch_bounds__(256, 2) void ca_attn3(
    const short* __restrict__ qb, const short* __restrict__ kb, const short* __restrict__ vt,
    short* __restrict__ pO, float* __restrict__ pL, int N) {
  __shared__ short Kl[2][4096];   // [buf][chunk(t4*2+ks)*512 + lane*8]
  __shared__ short Vl[2][4096];   // [buf][chunk(ks2*4+dt)*512 + lane*8]
  __shared__ short Pl[4][32][72];
  const int t = threadIdx.x, lane = t & 63, wid = t >> 6;
  const int g = lane >> 4, li = lane & 15;
  const int bid = blockIdx.x;
  const int sp = (bid >> 1) & 7;                 // same-CU blocks (b, b+256) share sp
  const int qblk = (bid >> 4) * 2 + (bid & 1);
  const int i0 = qblk * 128 + wid * 32;
  const int k0 = sp * (N >> 3);
  const int ntil = N >> 9;  // 16 tiles of 64 keys

  const short* ksrc = kb + ((size_t)(wid * 16 + li)) * 64 + g * 8;
  const short* vsrc0 = vt + (size_t)(li + ((2 * wid) & 3) * 16) * N + (wid >> 1) * 32 + g * 8;
  const short* vsrc1 = vt + (size_t)(li + ((2 * wid + 1) & 3) * 16) * N + (wid >> 1) * 32 + g * 8;

#define STAGE_TILE(b, j0)                                                \
  do {                                                                   \
    gload16(ksrc + (size_t)(j0) * 64,       &Kl[b][(2 * wid) * 512]);    \
    gload16(ksrc + (size_t)(j0) * 64 + 32,  &Kl[b][(2 * wid + 1) * 512]);\
    gload16(vsrc0 + (j0),                   &Vl[b][(2 * wid) * 512]);    \
    gload16(vsrc1 + (j0),                   &Vl[b][(2 * wid + 1) * 512]);\
  } while (0)

  short8 qa[2][2];
#pragma unroll
  for (int qs = 0; qs < 2; ++qs)
#pragma unroll
    for (int ks = 0; ks < 2; ++ks)
      qa[qs][ks] = *(const short8*)&qb[(size_t)(i0 + qs * 16 + li) * 64 + g * 8 + ks * 32];

  f32x4 acc[2][4], accs[2];
#pragma unroll
  for (int qs = 0; qs < 2; ++qs) {
#pragma unroll
    for (int n = 0; n < 4; ++n) acc[qs][n] = (f32x4){0.f, 0.f, 0.f, 0.f};
    accs[qs] = (f32x4){0.f, 0.f, 0.f, 0.f};
  }
  const short onev = (li == 0) ? (short)0x3F80 : (short)0;
  short8 ones;
#pragma unroll
  for (int j = 0; j < 8; ++j) ones[j] = onev;

  STAGE_TILE(0, k0);
  asm volatile("s_waitcnt vmcnt(0)" ::: "memory");

  for (int tt = 0; tt < ntil; ++tt) {
    const int cur = tt & 1;
    __builtin_amdgcn_s_barrier();
    if (tt + 1 < ntil) STAGE_TILE(cur ^ 1, k0 + (tt + 1) * 64);

    f32x4 s4[2][4];
#pragma unroll
    for (int qs = 0; qs < 2; ++qs)
#pragma unroll
      for (int t4 = 0; t4 < 4; ++t4) s4[qs][t4] = (f32x4){0.f, 0.f, 0.f, 0.f};
    __builtin_amdgcn_s_setprio(1);
#pragma unroll
    for (int ks = 0; ks < 2; ++ks)
#pragma unroll
      for (int t4 = 0; t4 < 4; ++t4) {
        short8 kf = *(const short8*)&Kl[cur][(t4 * 2 + ks) * 512 + lane * 8];
        s4[0][t4] = __builtin_amdgcn_mfma_f32_16x16x32_bf16(qa[0][ks], kf, s4[0][t4], 0, 0, 0);
        s4[1][t4] = __builtin_amdgcn_mfma_f32_16x16x32_bf16(qa[1][ks], kf, s4[1][t4], 0, 0, 0);
      }
    __builtin_amdgcn_s_setprio(0);
#pragma unroll
    for (int qs = 0; qs < 2; ++qs)
#pragma unroll
      for (int t4 = 0; t4 < 4; ++t4)
#pragma unroll
        for (int r = 0; r < 4; ++r) {
          float pe;
          asm("v_exp_f32 %0, %1" : "=v"(pe) : "v"(s4[qs][t4][r]));
          union { float f; unsigned u; } cv; cv.f = pe;
          Pl[wid][qs * 16 + g * 4 + r][li + t4 * 16] = (short)(cv.u >> 16);
        }
    asm volatile("s_waitcnt lgkmcnt(0)" ::: "memory");
    short8 pa[2][2];
#pragma unroll
    for (int qs = 0; qs < 2; ++qs)
#pragma unroll
      for (int ks2 = 0; ks2 < 2; ++ks2)
        pa[qs][ks2] = *(const short8*)&Pl[wid][qs * 16 + li][g * 8 + ks2 * 32];
    __builtin_amdgcn_s_setprio(1);
#pragma unroll
    for (int ks2 = 0; ks2 < 2; ++ks2) {
      accs[0] = __builtin_amdgcn_mfma_f32_16x16x32_bf16(pa[0][ks2], ones, accs[0], 0, 0, 0);
      accs[1] = __builtin_amdgcn_mfma_f32_16x16x32_bf16(pa[1][ks2], ones, accs[1], 0, 0, 0);
#pragma unroll
      for (int dt = 0; dt < 4; ++dt) {
        short8 vf = *(const short8*)&Vl[cur][(ks2 * 4 + dt) * 512 + lane * 8];
        acc[0][dt] = __builtin_amdgcn_mfma_f32_16x16x32_bf16(pa[0][ks2], vf, acc[0][dt], 0, 0, 0);
        acc[1][dt] = __builtin_amdgcn_mfma_f32_16x16x32_bf16(pa[1][ks2], vf, acc[1][dt], 0, 0, 0);
      }
    }
    __builtin_amdgcn_s_setprio(0);
    asm volatile("s_waitcnt vmcnt(0)" ::: "memory");
  }

  const size_t base = (size_t)sp * N + i0;
#pragma unroll
  for (int qs = 0; qs < 2; ++qs) {
#pragma unroll
    for (int dt = 0; dt < 4; ++dt)
#pragma unroll
      for (int r = 0; r < 4; ++r)
        pO[(base + qs * 16 + g * 4 + r) * 64 + li + dt * 16] = f2bf(acc[qs][dt][r]);
    if (li == 0) {
#pragma unroll
      for (int r = 0; r < 4; ++r)
        pL[(size_t)sp * N + i0 + qs * 16 + g * 4 + r] = accs[qs][r];
    }
  }
#undef STAGE_TILE
}

// ---------------- K3: merge 8 splits + residual + cross-attn + score + gate ----------------
__global__ __launch_bounds__(256) void ca_merge(
    const short* __restrict__ hb, const short* __restrict__ pO, const float* __restrict__ pL,
    const float* __restrict__ u_ws, const float* __restrict__ scal,
    const float* __restrict__ bil, const float* __restrict__ Wsc,
    const float* __restrict__ bsc_p, const float* __restrict__ rgate_p,
    float* __restrict__ out, int N) {
  const int t = threadIdx.x;
  const int row = blockIdx.x * 32 + (t >> 3), e = t & 7, d0 = e * 8;
  float L = 0.f;
#pragma unroll
  for (int sp = 0; sp < 8; ++sp) L += pL[(size_t)sp * N + row];
  float o[8];
#pragma unroll
  for (int i = 0; i < 8; ++i) o[i] = 0.f;
#pragma unroll
  for (int sp = 0; sp < 8; ++sp) {
    short8 ov = *(const short8*)&pO[((size_t)sp * N + row) * 64 + d0];
#pragma unroll
    for (int i = 0; i < 8; ++i) o[i] += bf2f(ov[i]);
  }
  const float invL = 1.f / L;
  short8 hv = *(const short8*)&hb[(size_t)row * 64 + d0];
  float s1 = 0.f, s2 = 0.f;
#pragma unroll
  for (int i = 0; i < 8; ++i) {
    float h2 = bf2f(hv[i]) + o[i] * invL;
    s1 += h2 * u_ws[d0 + i];
    s2 += h2 * Wsc[d0 + i];
  }
#pragma unroll
  for (int mask = 1; mask < 8; mask <<= 1) {
    s1 += __shfl_xor(s1, mask, 64);
    s2 += __shfl_xor(s2, mask, 64);
  }
  if (e == 0) {
    float gate = 1.f / (1.f + __expf(-rgate_p[0]));
    float caw = 1.f / (1.f + __expf(-(s1 + scal[0]) * 0.125f));
    float score = s2 + caw * scal[1] + bsc_p[0];
    out[row] = (1.f - gate) * bil[row] + gate * score;
  }
}

extern "C" void kernel_launch(void* const* d_in, const int* in_sizes, int n_in,
                              void* d_out, int out_size, void* d_ws, size_t ws_size,
                              hipStream_t stream) {
  const float* sit  = (const float*)d_in[0];
  const float* te   = (const float*)d_in[1];
  const float* bil  = (const float*)d_in[2];
  const float* Wt   = (const float*)d_in[3];
  const float* bt   = (const float*)d_in[4];
  const float* Ws   = (const float*)d_in[5];
  const float* bs   = (const float*)d_in[6];
  const float* Wsaq = (const float*)d_in[7];
  const float* bsaq = (const float*)d_in[8];
  const float* Wsak = (const float*)d_in[9];
  const float* bsak = (const float*)d_in[10];
  const float* Wsav = (const float*)d_in[11];
  const float* bsav = (const float*)d_in[12];
  const float* Wcq  = (const float*)d_in[13];
  const float* bcq  = (const float*)d_in[14];
  const float* Wck  = (const float*)d_in[15];
  const float* bck  = (const float*)d_in[16];
  const float* Wcv  = (const float*)d_in[17];
  const float* bcv  = (const float*)d_in[18];
  const float* Wsc  = (const float*)d_in[19];
  const float* bsc  = (const float*)d_in[20];
  const float* rgate= (const float*)d_in[21];
  const int N = in_sizes[2];

  char* w = (char*)d_ws;
  size_t off = 0;
  short* hbuf  = (short*)(w + off); off += (size_t)N * 64 * 2;
  short* qbuf  = (short*)(w + off); off += (size_t)N * 64 * 2;
  short* kbuf  = (short*)(w + off); off += (size_t)N * 64 * 2;
  short* vtbuf = (short*)(w + off); off += (size_t)N * 64 * 2;
  float* u_ws  = (float*)(w + off); off += 64 * 4;
  float* scal  = (float*)(w + off); off += 4 * 4;
  short* Wtb   = (short*)(w + off); off += 24576 * 2;
  float* wcol  = (float*)(w + off); off += 64 * 4;
  short* Wqb   = (short*)(w + off); off += 4096 * 2;
  short* Wkb   = (short*)(w + off); off += 4096 * 2;
  short* Wvb   = (short*)(w + off); off += 4096 * 2;
  short* pO    = (short*)(w + off); off += (size_t)8 * N * 64 * 2;
  float* pL    = (float*)(w + off); off += (size_t)8 * N * 4;

  ca_setup<<<146, 256, 0, stream>>>(Wt, Wsaq, Wsak, Wsav, Wtb, wcol, Wqb, Wkb, Wvb,
                                    sit, Ws, bs, Wck, bck, Wcv, bcv, Wcq, bcq, Wsc, u_ws, scal);
  ca_proj<<<N / 64, 256, 0, stream>>>(te, bil, Wtb, wcol, bt, Wqb, bsaq, Wkb, bsak, Wvb, bsav,
                                      hbuf, qbuf, kbuf, vtbuf, N);
  ca_attn3<<<N / 16, 256, 0, stream>>>(qbuf, kbuf, vtbuf, pO, pL, N);
  ca_merge<<<N / 32, 256, 0, stream>>>(hbuf, pO, pL, u_ws, scal, bil, Wsc, bsc, rgate,
                                       (float*)d_out, N);
}

// Round 6
// 56.443 us; speedup vs baseline: 6.5456x; 1.1431x over previous
//
#include <hip/hip_runtime.h>
#include <hip/hip_bf16.h>

typedef __attribute__((ext_vector_type(8))) short short8;
typedef __attribute__((ext_vector_type(4))) float f32x4;

__device__ __forceinline__ short f2bf(float x) {
  union { float f; unsigned u; } a; a.f = x;
  unsigned r = (a.u + 0x7FFFu + ((a.u >> 16) & 1u)) >> 16;
  return (short)r;
}
__device__ __forceinline__ float bf2f(short x) {
  union { unsigned u; float f; } a; a.u = ((unsigned)(unsigned short)x) << 16;
  return a.f;
}
__device__ __forceinline__ unsigned cvtpk(float lo, float hi) {
  unsigned r;
  asm("v_cvt_pk_bf16_f32 %0, %1, %2" : "=v"(r) : "v"(lo), "v"(hi));
  return r;
}
__device__ __forceinline__ void gload16(const void* g, void* l) {
  __builtin_amdgcn_global_load_lds((const __attribute__((address_space(1))) unsigned int*)g,
                                   (__attribute__((address_space(3))) unsigned int*)l, 16, 0, 0);
}

// ---------------- K0: setup = Wt conversion (blocks 0..96) + situation path (block 97) ----------
__global__ __launch_bounds__(256) void ca_setup2(
    const float* __restrict__ Wt, short* __restrict__ Wtb, float* __restrict__ wcol,
    const float* __restrict__ sit, const float* __restrict__ Ws, const float* __restrict__ bs,
    const float* __restrict__ Wck, const float* __restrict__ bck, const float* __restrict__ Wcv,
    const float* __restrict__ bcv, const float* __restrict__ Wcq, const float* __restrict__ bcq,
    const float* __restrict__ Wsc, float* __restrict__ u_ws, float* __restrict__ scal) {
  const int bid = blockIdx.x, t = threadIdx.x;
  if (bid < 97) {
    int idx = bid * 256 + t;
    if (idx < 24576) {
      int r = idx / 384, c = idx % 384;
      Wtb[idx] = f2bf(Wt[r * 385 + c]);
    } else if (idx < 24640) {
      wcol[idx - 24576] = Wt[(idx - 24576) * 385 + 384];
    }
    return;
  }
  __shared__ float part[4][64];
  __shared__ float sh[64], ck[64], cv[64];
  int j = t & 63, p = t >> 6;
  float a = 0.f;
  for (int d = p * 96; d < p * 96 + 96; ++d) a += Ws[j * 384 + d] * sit[d];
  part[p][j] = a;
  __syncthreads();
  if (t < 64) sh[t] = part[0][t] + part[1][t] + part[2][t] + part[3][t] + bs[t];
  __syncthreads();
  if (t < 64) {
    float kk = bck[t], vv = bcv[t];
    for (int d = 0; d < 64; ++d) { kk += Wck[t * 64 + d] * sh[d]; vv += Wcv[t * 64 + d] * sh[d]; }
    ck[t] = kk; cv[t] = vv;
  }
  __syncthreads();
  if (t < 64) {
    float uu = 0.f;
    for (int jj = 0; jj < 64; ++jj) uu += Wcq[jj * 64 + t] * ck[jj];
    u_ws[t] = uu;
  }
  if (t == 0) {
    float c0 = 0.f, cw = 0.f;
    for (int jj = 0; jj < 64; ++jj) { c0 += bcq[jj] * ck[jj]; cw += cv[jj] * Wsc[jj]; }
    scal[0] = c0; scal[1] = cw;
  }
}

// ---------------- K1: fused projections, full-GPU grid (N/32 blocks, 256 thr) ----------------
// Phase A: hidden GEMM K-split 4 ways (wave w: k in [96w,96w+96)) + LDS partial reduce.
// Phase B: q/k/v GEMMs, n-split across waves (wave w owns output cols w*16..+15).
__global__ __launch_bounds__(256) void ca_proj2(
    const float* __restrict__ te, const float* __restrict__ bil,
    const short* __restrict__ Wtb, const float* __restrict__ wcol2, const float* __restrict__ bt,
    const float* __restrict__ Wsaq, const float* __restrict__ bq,
    const float* __restrict__ Wsak, const float* __restrict__ bk2,
    const float* __restrict__ Wsav, const float* __restrict__ bv,
    short* __restrict__ hb, short* __restrict__ qb, short* __restrict__ kb,
    short* __restrict__ vt, int N) {
  __shared__ float Pp[8192];       // [w(4)][qs(2)][n(4)][lane(64)][4] f32 = 32 KB
  __shared__ short Hl[32][72];
  __shared__ short Vt[64][40];
  const int t = threadIdx.x, lane = t & 63, w = t >> 6;
  const int g = lane >> 4, li = lane & 15;
  const int i0 = blockIdx.x * 32;

  // ---- phase A: partial hidden GEMM over this wave's k-range ----
  f32x4 acc[2][4];
#pragma unroll
  for (int qs = 0; qs < 2; ++qs)
#pragma unroll
    for (int n = 0; n < 4; ++n) acc[qs][n] = (f32x4){0.f, 0.f, 0.f, 0.f};
  const int kw = w * 96;
#pragma unroll
  for (int ks = 0; ks < 3; ++ks) {
    short8 af[2];
#pragma unroll
    for (int qs = 0; qs < 2; ++qs) {
      const float* ap = te + (size_t)(i0 + qs * 16 + li) * 384 + kw + ks * 32 + g * 8;
      float4 a0 = *(const float4*)ap;
      float4 a1 = *(const float4*)(ap + 4);
      af[qs][0] = f2bf(a0.x); af[qs][1] = f2bf(a0.y); af[qs][2] = f2bf(a0.z); af[qs][3] = f2bf(a0.w);
      af[qs][4] = f2bf(a1.x); af[qs][5] = f2bf(a1.y); af[qs][6] = f2bf(a1.z); af[qs][7] = f2bf(a1.w);
    }
#pragma unroll
    for (int n = 0; n < 4; ++n) {
      short8 bf = *(const short8*)&Wtb[(size_t)(n * 16 + li) * 384 + kw + ks * 32 + g * 8];
      acc[0][n] = __builtin_amdgcn_mfma_f32_16x16x32_bf16(af[0], bf, acc[0][n], 0, 0, 0);
      acc[1][n] = __builtin_amdgcn_mfma_f32_16x16x32_bf16(af[1], bf, acc[1][n], 0, 0, 0);
    }
  }
#pragma unroll
  for (int qs = 0; qs < 2; ++qs)
#pragma unroll
    for (int n = 0; n < 4; ++n)
      *(f32x4*)&Pp[((w * 8 + qs * 4 + n) * 64 + lane) * 4] = acc[qs][n];
  __syncthreads();
  // reduce 4 k-partials + bias + rank-1 bil term -> Hl (bf16)
#pragma unroll
  for (int ss = 0; ss < 2; ++ss) {
    int s = t + ss * 256;
    int qs2 = s >> 8, n2 = (s >> 6) & 3, lane2 = s & 63;
    int g2 = lane2 >> 4, li2 = lane2 & 15;
    int base = (qs2 * 4 + n2) * 256 + lane2 * 4;
    f32x4 v0 = *(const f32x4*)&Pp[base];
    f32x4 v1 = *(const f32x4*)&Pp[base + 2048];
    f32x4 v2 = *(const f32x4*)&Pp[base + 4096];
    f32x4 v3 = *(const f32x4*)&Pp[base + 6144];
    int col = n2 * 16 + li2;
    float wc = wcol2[col], bb = bt[col];
#pragma unroll
    for (int r = 0; r < 4; ++r) {
      int row = qs2 * 16 + g2 * 4 + r;
      float val = v0[r] + v1[r] + v2[r] + v3[r] + bb + bil[i0 + row] * wc;
      Hl[row][col] = f2bf(val);
    }
  }
  __syncthreads();
  // vectorized hb write
  {
    int row = t >> 3, seg = t & 7;
    *(uint4*)&hb[(size_t)(i0 + row) * 64 + seg * 8] = *(uint4*)&Hl[row][seg * 8];
  }
  // ---- phase B: q/k/v (wave w owns output cols w*16..+15) ----
  short8 ha[2][2];
#pragma unroll
  for (int qs = 0; qs < 2; ++qs)
#pragma unroll
    for (int ks = 0; ks < 2; ++ks)
      ha[qs][ks] = *(const short8*)&Hl[qs * 16 + li][ks * 32 + g * 8];
  const float* Wm[3] = {Wsaq, Wsak, Wsav};
  f32x4 pacc[3][2];
#pragma unroll
  for (int m = 0; m < 3; ++m)
#pragma unroll
    for (int qs = 0; qs < 2; ++qs) pacc[m][qs] = (f32x4){0.f, 0.f, 0.f, 0.f};
#pragma unroll
  for (int m = 0; m < 3; ++m)
#pragma unroll
    for (int ks = 0; ks < 2; ++ks) {
      const float* wp = Wm[m] + (size_t)(w * 16 + li) * 64 + ks * 32 + g * 8;
      float4 b0 = *(const float4*)wp;
      float4 b1 = *(const float4*)(wp + 4);
      short8 bf;
      bf[0] = f2bf(b0.x); bf[1] = f2bf(b0.y); bf[2] = f2bf(b0.z); bf[3] = f2bf(b0.w);
      bf[4] = f2bf(b1.x); bf[5] = f2bf(b1.y); bf[6] = f2bf(b1.z); bf[7] = f2bf(b1.w);
      pacc[m][0] = __builtin_amdgcn_mfma_f32_16x16x32_bf16(ha[0][ks], bf, pacc[m][0], 0, 0, 0);
      pacc[m][1] = __builtin_amdgcn_mfma_f32_16x16x32_bf16(ha[1][ks], bf, pacc[m][1], 0, 0, 0);
    }
  const int col = w * 16 + li;
  const float QSC = 0.18033688011112042f;  // log2(e)/8
  {
    float bbq = bq[col], bbk = bk2[col], bbv = bv[col];
#pragma unroll
    for (int qs = 0; qs < 2; ++qs)
#pragma unroll
      for (int r = 0; r < 4; ++r) {
        int row = i0 + qs * 16 + g * 4 + r;
        qb[(size_t)row * 64 + col] = f2bf((pacc[0][qs][r] + bbq) * QSC);
        kb[(size_t)row * 64 + col] = f2bf(pacc[1][qs][r] + bbk);
        Vt[col][qs * 16 + g * 4 + r] = f2bf(pacc[2][qs][r] + bbv);
      }
  }
  __syncthreads();
  {
    int c = t >> 2, seg = t & 3;
    *(uint4*)&vt[(size_t)c * N + i0 + seg * 8] = *(uint4*)&Vt[c][seg * 8];
  }
}

// ---------------- K2: LDS-staged attention, swapped QK^T, lane-local P, 8-way key split -------
__global__ __launch_bounds__(256, 2) void ca_attn4(
    const short* __restrict__ qb, const short* __restrict__ kb, const short* __restrict__ vt,
    short* __restrict__ pO, float* __restrict__ pL, int N) {
  __shared__ short Kl[2][4096];
  __shared__ short Vl[2][4096];
  __shared__ short Pl[4][32][72];
  const int t = threadIdx.x, lane = t & 63, wid = t >> 6;
  const int g = lane >> 4, li = lane & 15;
  const int bid = blockIdx.x;
  const int sp = (bid >> 1) & 7;                 // same-CU blocks (b, b+256) share sp
  const int qblk = (bid >> 4) * 2 + (bid & 1);
  const int i0 = qblk * 128 + wid * 32;
  const int k0 = sp * (N >> 3);
  const int ntil = N >> 9;

  const short* ksrc = kb + ((size_t)(wid * 16 + li)) * 64 + g * 8;
  const short* vsrc0 = vt + (size_t)(li + ((2 * wid) & 3) * 16) * N + (wid >> 1) * 32 + g * 8;
  const short* vsrc1 = vt + (size_t)(li + ((2 * wid + 1) & 3) * 16) * N + (wid >> 1) * 32 + g * 8;

#define STAGE_TILE(b, j0)                                                \
  do {                                                                   \
    gload16(ksrc + (size_t)(j0) * 64,       &Kl[b][(2 * wid) * 512]);    \
    gload16(ksrc + (size_t)(j0) * 64 + 32,  &Kl[b][(2 * wid + 1) * 512]);\
    gload16(vsrc0 + (j0),                   &Vl[b][(2 * wid) * 512]);    \
    gload16(vsrc1 + (j0),                   &Vl[b][(2 * wid + 1) * 512]);\
  } while (0)

  short8 qa[2][2];
#pragma unroll
  for (int qs = 0; qs < 2; ++qs)
#pragma unroll
    for (int ks = 0; ks < 2; ++ks)
      qa[qs][ks] = *(const short8*)&qb[(size_t)(i0 + qs * 16 + li) * 64 + g * 8 + ks * 32];

  f32x4 acc[2][4];
  float rs[2] = {0.f, 0.f};
#pragma unroll
  for (int qs = 0; qs < 2; ++qs)
#pragma unroll
    for (int n = 0; n < 4; ++n) acc[qs][n] = (f32x4){0.f, 0.f, 0.f, 0.f};

  STAGE_TILE(0, k0);
  asm volatile("s_waitcnt vmcnt(0)" ::: "memory");

  for (int tt = 0; tt < ntil; ++tt) {
    const int cur = tt & 1;
    __builtin_amdgcn_s_barrier();
    if (tt + 1 < ntil) STAGE_TILE(cur ^ 1, k0 + (tt + 1) * 64);

    // ---- swapped QK^T: s4[qs][t4] rows = k-local (g*4+r), cols = q-local (li) ----
    f32x4 s4[2][4];
#pragma unroll
    for (int qs = 0; qs < 2; ++qs)
#pragma unroll
      for (int t4 = 0; t4 < 4; ++t4) s4[qs][t4] = (f32x4){0.f, 0.f, 0.f, 0.f};
    __builtin_amdgcn_s_setprio(1);
#pragma unroll
    for (int ks = 0; ks < 2; ++ks)
#pragma unroll
      for (int t4 = 0; t4 < 4; ++t4) {
        short8 kf = *(const short8*)&Kl[cur][(t4 * 2 + ks) * 512 + lane * 8];
        s4[0][t4] = __builtin_amdgcn_mfma_f32_16x16x32_bf16(kf, qa[0][ks], s4[0][t4], 0, 0, 0);
        s4[1][t4] = __builtin_amdgcn_mfma_f32_16x16x32_bf16(kf, qa[1][ks], s4[1][t4], 0, 0, 0);
      }
    __builtin_amdgcn_s_setprio(0);
    // ---- p = 2^s (lane-local q-row li): exp, in-reg rowsum, cvt_pk, b64 LDS writes ----
#pragma unroll
    for (int qs = 0; qs < 2; ++qs) {
#pragma unroll
      for (int t4 = 0; t4 < 4; ++t4) {
        float p0, p1, p2, p3;
        asm("v_exp_f32 %0, %1" : "=v"(p0) : "v"(s4[qs][t4][0]));
        asm("v_exp_f32 %0, %1" : "=v"(p1) : "v"(s4[qs][t4][1]));
        asm("v_exp_f32 %0, %1" : "=v"(p2) : "v"(s4[qs][t4][2]));
        asm("v_exp_f32 %0, %1" : "=v"(p3) : "v"(s4[qs][t4][3]));
        rs[qs] += (p0 + p1) + (p2 + p3);
        uint2 wv;
        wv.x = cvtpk(p0, p1);
        wv.y = cvtpk(p2, p3);
        *(uint2*)&Pl[wid][qs * 16 + li][t4 * 16 + g * 4] = wv;
      }
    }
    asm volatile("s_waitcnt lgkmcnt(0)" ::: "memory");
    // ---- PV from LDS-P (A-operand layout) ----
    short8 pa[2][2];
#pragma unroll
    for (int qs = 0; qs < 2; ++qs)
#pragma unroll
      for (int ks2 = 0; ks2 < 2; ++ks2)
        pa[qs][ks2] = *(const short8*)&Pl[wid][qs * 16 + li][g * 8 + ks2 * 32];
    __builtin_amdgcn_s_setprio(1);
#pragma unroll
    for (int ks2 = 0; ks2 < 2; ++ks2)
#pragma unroll
      for (int dt = 0; dt < 4; ++dt) {
        short8 vf = *(const short8*)&Vl[cur][(ks2 * 4 + dt) * 512 + lane * 8];
        acc[0][dt] = __builtin_amdgcn_mfma_f32_16x16x32_bf16(pa[0][ks2], vf, acc[0][dt], 0, 0, 0);
        acc[1][dt] = __builtin_amdgcn_mfma_f32_16x16x32_bf16(pa[1][ks2], vf, acc[1][dt], 0, 0, 0);
      }
    __builtin_amdgcn_s_setprio(0);
    asm volatile("s_waitcnt vmcnt(0)" ::: "memory");
  }

  const size_t base = (size_t)sp * N + i0;
#pragma unroll
  for (int qs = 0; qs < 2; ++qs) {
#pragma unroll
    for (int dt = 0; dt < 4; ++dt)
#pragma unroll
      for (int r = 0; r < 4; ++r)
        pO[(base + qs * 16 + g * 4 + r) * 64 + li + dt * 16] = f2bf(acc[qs][dt][r]);
    float r2 = rs[qs] + __shfl_xor(rs[qs], 16, 64);
    r2 += __shfl_xor(r2, 32, 64);
    if (lane < 16) pL[(size_t)sp * N + i0 + qs * 16 + lane] = r2;
  }
#undef STAGE_TILE
}

// ---------------- K3: merge 8 splits + residual + cross-attn + score + gate ----------------
__global__ __launch_bounds__(256) void ca_merge(
    const short* __restrict__ hb, const short* __restrict__ pO, const float* __restrict__ pL,
    const float* __restrict__ u_ws, const float* __restrict__ scal,
    const float* __restrict__ bil, const float* __restrict__ Wsc,
    const float* __restrict__ bsc_p, const float* __restrict__ rgate_p,
    float* __restrict__ out, int N) {
  const int t = threadIdx.x;
  const int row = blockIdx.x * 32 + (t >> 3), e = t & 7, d0 = e * 8;
  float L = 0.f;
#pragma unroll
  for (int sp = 0; sp < 8; ++sp) L += pL[(size_t)sp * N + row];
  float o[8];
#pragma unroll
  for (int i = 0; i < 8; ++i) o[i] = 0.f;
#pragma unroll
  for (int sp = 0; sp < 8; ++sp) {
    short8 ov = *(const short8*)&pO[((size_t)sp * N + row) * 64 + d0];
#pragma unroll
    for (int i = 0; i < 8; ++i) o[i] += bf2f(ov[i]);
  }
  const float invL = 1.f / L;
  short8 hv = *(const short8*)&hb[(size_t)row * 64 + d0];
  float s1 = 0.f, s2 = 0.f;
#pragma unroll
  for (int i = 0; i < 8; ++i) {
    float h2 = bf2f(hv[i]) + o[i] * invL;
    s1 += h2 * u_ws[d0 + i];
    s2 += h2 * Wsc[d0 + i];
  }
#pragma unroll
  for (int mask = 1; mask < 8; mask <<= 1) {
    s1 += __shfl_xor(s1, mask, 64);
    s2 += __shfl_xor(s2, mask, 64);
  }
  if (e == 0) {
    float gate = 1.f / (1.f + __expf(-rgate_p[0]));
    float caw = 1.f / (1.f + __expf(-(s1 + scal[0]) * 0.125f));
    float score = s2 + caw * scal[1] + bsc_p[0];
    out[row] = (1.f - gate) * bil[row] + gate * score;
  }
}

extern "C" void kernel_launch(void* const* d_in, const int* in_sizes, int n_in,
                              void* d_out, int out_size, void* d_ws, size_t ws_size,
                              hipStream_t stream) {
  const float* sit  = (const float*)d_in[0];
  const float* te   = (const float*)d_in[1];
  const float* bil  = (const float*)d_in[2];
  const float* Wt   = (const float*)d_in[3];
  const float* bt   = (const float*)d_in[4];
  const float* Ws   = (const float*)d_in[5];
  const float* bs   = (const float*)d_in[6];
  const float* Wsaq = (const float*)d_in[7];
  const float* bsaq = (const float*)d_in[8];
  const float* Wsak = (const float*)d_in[9];
  const float* bsak = (const float*)d_in[10];
  const float* Wsav = (const float*)d_in[11];
  const float* bsav = (const float*)d_in[12];
  const float* Wcq  = (const float*)d_in[13];
  const float* bcq  = (const float*)d_in[14];
  const float* Wck  = (const float*)d_in[15];
  const float* bck  = (const float*)d_in[16];
  const float* Wcv  = (const float*)d_in[17];
  const float* bcv  = (const float*)d_in[18];
  const float* Wsc  = (const float*)d_in[19];
  const float* bsc  = (const float*)d_in[20];
  const float* rgate= (const float*)d_in[21];
  const int N = in_sizes[2];

  char* w = (char*)d_ws;
  size_t off = 0;
  short* hbuf  = (short*)(w + off); off += (size_t)N * 64 * 2;
  short* qbuf  = (short*)(w + off); off += (size_t)N * 64 * 2;
  short* kbuf  = (short*)(w + off); off += (size_t)N * 64 * 2;
  short* vtbuf = (short*)(w + off); off += (size_t)N * 64 * 2;
  float* u_ws  = (float*)(w + off); off += 64 * 4;
  float* scal  = (float*)(w + off); off += 4 * 4;
  short* Wtb   = (short*)(w + off); off += 24576 * 2;
  float* wcol  = (float*)(w + off); off += 64 * 4;
  short* pO    = (short*)(w + off); off += (size_t)8 * N * 64 * 2;
  float* pL    = (float*)(w + off); off += (size_t)8 * N * 4;

  ca_setup2<<<98, 256, 0, stream>>>(Wt, Wtb, wcol, sit, Ws, bs, Wck, bck, Wcv, bcv,
                                    Wcq, bcq, Wsc, u_ws, scal);
  ca_proj2<<<N / 32, 256, 0, stream>>>(te, bil, Wtb, wcol, bt, Wsaq, bsaq, Wsak, bsak,
                                       Wsav, bsav, hbuf, qbuf, kbuf, vtbuf, N);
  ca_attn4<<<N / 16, 256, 0, stream>>>(qbuf, kbuf, vtbuf, pO, pL, N);
  ca_merge<<<N / 32, 256, 0, stream>>>(hbuf, pO, pL, u_ws, scal, bil, Wsc, bsc, rgate,
                                       (float*)d_out, N);
}